// Round 9
// baseline (248.369 us; speedup 1.0000x reference)
//
#include <hip/hip_runtime.h>
#include <math.h>

// Problem constants
#define B_   2
#define T_   2048
#define D_   1024
#define C_   10
#define F_   513
#define NTOK (B_ * T_)     // 4096 rows
#define KOFF 1028          // us16 col offset of k section (u32 514, 8B aligned)
#define VOFF 2056          // us16 col offset of v section (u32 1028, 8B aligned)
#define LFU  3082          // used Fall cols incl 2-col gaps (q|gap|k|gap|v)
#define LFP  3136          // Fall row stride (us16): 6272 B, line-aligned rows
#define MROWS 1028         // MallB batch row stride (2-row gap after 1026)
#define KP2  1056          // padded K for output GEMM (cols 0..1025 used, pad 30)
#define NCH  256           // scan chunks (R13: was 128 -> 2x TLP)
#define TC   (T_ / NCH)    // 8 timesteps per chunk

typedef unsigned short us16;
typedef __attribute__((ext_vector_type(8))) __bf16 bf16x8;
typedef __attribute__((ext_vector_type(4))) float  f32x4;

// Workspace layout (bytes). RCAT aliases PREP (WT+WoBf+Tcs, 10.49 MB >=
// 8.65 MB needed; all builders finish before scan_apply writes).
#define O_XBF    ((size_t)0)                 // x bf16: 8,388,608
#define O_PREP   ((size_t)8388608)
#define O_WT     (O_PREP)                    // WT bf16 3x1024x1024: 6,291,456
#define O_WOBF   (O_PREP + 6291456)          // Wo bf16: 2,097,152
#define O_TCS    (O_PREP + 8388608)          // Tcs bf16 1026x1024: 2,101,248
#define O_RCAT   (O_PREP)                    // Rcat bf16 4096x1056: 8,650,752
#define O_SFB    (O_PREP + 10489856)         // Sfb bf16 1056x1024: 2,162,688
#define O_MALLB  (O_SFB + 2162688)           // Mall bf16 3x1028x1024: 6,316,032
#define O_MOUTB  (O_MALLB + 6316032)         // MoutT bf16 1024x1056: 2,162,688
#define O_FALL   (O_MOUTB + 2162688)         // Fall bf16 4096x3136: 25,690,112
#define O_SSCAN  (O_FALL + 25690112)         // scan sums fp32: 21,012,480

__device__ __forceinline__ us16 f2b(float f) {
    union { float f; unsigned u; } v; v.f = f;
    unsigned r = v.u + 0x7FFFu + ((v.u >> 16) & 1u);
    return (us16)(r >> 16);
}

// packed bf16 pair -> float2 (bit-exact)
__device__ __forceinline__ float2 b2f2(unsigned w) {
    union { unsigned u; float f; } a, b;
    a.u = (w & 0xffffu) << 16;
    b.u = w & 0xffff0000u;
    return make_float2(a.f, b.f);
}

// async global->LDS DMA, 16 B per lane. LDS dest is wave-uniform base +
// lane*16 (HW-fixed); global src is per-lane.
__device__ __forceinline__ void gl_lds16(const us16* g, us16* l) {
    __builtin_amdgcn_global_load_lds(
        (const __attribute__((address_space(1))) unsigned*)g,
        (__attribute__((address_space(3))) unsigned*)l, 16, 0, 0);
}

// ---------------------------------------------------------------------------
// Fused prep: x->bf16 | Wo->bf16 | W transpose x3 | Tcs | Sfb, one dispatch,
// 1D grid partitioned by block-id range (branch is block-uniform).
// ---------------------------------------------------------------------------
__global__ __launch_bounds__(256)
void hrr_prep(const float* __restrict__ x,  const float* __restrict__ Wq,
              const float* __restrict__ Wk, const float* __restrict__ Wv,
              const float* __restrict__ Wo,
              us16* __restrict__ Xbf, us16* __restrict__ WT,
              us16* __restrict__ WoBf, us16* __restrict__ Tcs,
              us16* __restrict__ Sfb) {
    __shared__ float t[32][33];
    const int bid = blockIdx.x, tid = threadIdx.x;
    if (bid < 4096) {
        int i = bid * 256 + tid;
        float4 v = ((const float4*)x)[i];
        ushort4 o;
        o.x = f2b(v.x); o.y = f2b(v.y); o.z = f2b(v.z); o.w = f2b(v.w);
        ((ushort4*)Xbf)[i] = o;
    } else if (bid < 5120) {
        int i = (bid - 4096) * 256 + tid;
        float4 v = ((const float4*)Wo)[i];
        ushort4 o;
        o.x = f2b(v.x); o.y = f2b(v.y); o.z = f2b(v.z); o.w = f2b(v.w);
        ((ushort4*)WoBf)[i] = o;
    } else if (bid < 8192) {
        const int l  = bid - 5120;
        const int bz = l >> 10, l2 = l & 1023;
        const int bx = (l2 & 31) * 32, by = (l2 >> 5) * 32;
        const float* W = (bz == 0) ? Wq : (bz == 1) ? Wk : Wv;
        us16* O = WT + (size_t)bz * D_ * D_;
        const int tx = tid & 31, ty = tid >> 5;   // 32 x 8
#pragma unroll
        for (int i = 0; i < 32; i += 8)
            t[ty + i][tx] = W[(size_t)(by + ty + i) * D_ + bx + tx];
        __syncthreads();
#pragma unroll
        for (int i = 0; i < 32; i += 8)
            O[(size_t)(bx + ty + i) * D_ + by + tx] = f2b(t[tx][ty + i]);
    } else if (bid < 12296) {
        // Tcs rows interleaved: row 2f = cos(2*pi*f*e/1024), 2f+1 = -sin
        int idx = (bid - 8192) * 256 + tid;
        int r = idx >> 10, e = idx & 1023;
        int f = r >> 1;
        float ang = (float)((f * e) & 1023) * 6.135923151542565e-3f;
        Tcs[idx] = f2b((r & 1) ? -sinf(ang) : cosf(ang));
    } else {
        // Sfb rows interleaved: 2f = s_f*cos, 2f+1 = -s_f*sin; pad rows 0
        int idx = (bid - 12296) * 256 + tid;
        int r = idx >> 10, e = idx & 1023;
        float v = 0.f;
        if (r < 1026) {
            int f = r >> 1;
            float s = (f == 0 || f == 512) ? (1.0f / 1024.0f) : (2.0f / 1024.0f);
            float ang = (float)((f * e) & 1023) * 6.135923151542565e-3f;
            v = (r & 1) ? -s * sinf(ang) : s * cosf(ang);
        }
        Sfb[idx] = f2b(v);
    }
}

// ---------------------------------------------------------------------------
// 128x128 bf16 MFMA GEMM core: C = A @ B^T. 2-buf, ONE barrier per K-step,
// gload_lds staging, granule XOR-swizzle (0 bank conflicts). Swapped mfma
// operands + LDS repack -> full-line row stores. Builders + output GEMM.
// ---------------------------------------------------------------------------
template <bool OUT_BF16>
__device__ __forceinline__ void gemm_core(
    const us16* __restrict__ A, const us16* __restrict__ B, void* __restrict__ Cv,
    int M, int N, int K, int lda, int ldb, int ldc, int Ncap,
    int bm, int bn, us16* smem) {
    us16* As = smem;
    us16* Bs = smem + 8192;

    const int tid  = threadIdx.x;
    const int lane = tid & 63;
    const int wave = tid >> 6;
    const int wm = (wave >> 1) * 64;
    const int wn = (wave & 1) * 64;

    const int r0    = tid >> 2;
    const int g_lds = tid & 3;
    const int g_src = g_lds ^ ((r0 >> 1) & 3);
    const int c4    = g_src * 8;

    int rA0 = bm + r0;      if (rA0 >= M) rA0 = M - 1;
    int rA1 = bm + 64 + r0; if (rA1 >= M) rA1 = M - 1;
    int rB0 = bn + r0;      if (rB0 >= N) rB0 = N - 1;
    int rB1 = bn + 64 + r0; if (rB1 >= N) rB1 = N - 1;
    const us16* pA0 = A + (size_t)rA0 * lda + c4;
    const us16* pA1 = A + (size_t)rA1 * lda + c4;
    const us16* pB0 = B + (size_t)rB0 * ldb + c4;
    const us16* pB1 = B + (size_t)rB1 * ldb + c4;

    f32x4 acc[4][4];
#pragma unroll
    for (int i = 0; i < 4; i++)
#pragma unroll
        for (int j = 0; j < 4; j++) acc[i][j] = (f32x4){0.f, 0.f, 0.f, 0.f};

    const int fr = lane & 15;
    const int gq = ((lane >> 4) ^ ((fr >> 1) & 3)) * 8;

    const int wb = wave * 512;
#define STAGE_TILE(buf, ko)                                  \
    do {                                                     \
        us16* a_ = As + (buf) * 4096 + wb;                   \
        us16* b_ = Bs + (buf) * 4096 + wb;                   \
        gl_lds16(pA0 + (ko), a_);                            \
        gl_lds16(pA1 + (ko), a_ + 2048);                     \
        gl_lds16(pB0 + (ko), b_);                            \
        gl_lds16(pB1 + (ko), b_ + 2048);                     \
    } while (0)

    STAGE_TILE(0, 0);
    __syncthreads();

    int cur = 0;
    for (int k0 = 0; k0 < K; k0 += 32) {
        const int kn = k0 + 32;
        if (kn < K) STAGE_TILE(cur ^ 1, kn);

        const us16* Ac = As + cur * 4096;
        const us16* Bc = Bs + cur * 4096;
        bf16x8 af[4], bfr[4];
#pragma unroll
        for (int i = 0; i < 4; i++)
            af[i] = *(const bf16x8*)(Ac + (wm + i * 16 + fr) * 32 + gq);
#pragma unroll
        for (int j = 0; j < 4; j++)
            bfr[j] = *(const bf16x8*)(Bs + cur * 4096 + (wn + j * 16 + fr) * 32 + gq);
#pragma unroll
        for (int i = 0; i < 4; i++)
#pragma unroll
            for (int j = 0; j < 4; j++)
                acc[i][j] = __builtin_amdgcn_mfma_f32_16x16x32_bf16(bfr[j], af[i], acc[i][j], 0, 0, 0);

        __syncthreads();
        cur ^= 1;
        (void)Bc;
    }
#undef STAGE_TILE

    const int cl  = lane & 15;
    const int rq  = (lane >> 4) * 4;
    float* lbuf = (float*)smem;
#pragma unroll
    for (int p = 0; p < 4; ++p) {
        __syncthreads();
        if ((wave >> 1) == (p >> 1)) {
            const int ib = (p & 1) * 2;
#pragma unroll
            for (int ii = 0; ii < 2; ++ii) {
                const int rl = ii * 16 + cl;
#pragma unroll
                for (int j = 0; j < 4; ++j)
                    *(f32x4*)(lbuf + rl * 132 + wn + j * 16 + rq) = acc[ib + ii][j];
            }
        }
        __syncthreads();
        const int rbase = bm + p * 32;
        if (OUT_BF16) {
            us16* C = (us16*)Cv;
#pragma unroll
            for (int rr = 0; rr < 2; ++rr) {
                const int idx = rr * 2048 + tid * 8;
                const int row = idx >> 7, col = idx & 127;
                const int grow = rbase + row, gcol = bn + col;
                if (grow < M && gcol + 8 <= Ncap) {
                    const float* s = lbuf + row * 132 + col;
                    uint4 o;
                    o.x = (unsigned)f2b(s[0]) | ((unsigned)f2b(s[1]) << 16);
                    o.y = (unsigned)f2b(s[2]) | ((unsigned)f2b(s[3]) << 16);
                    o.z = (unsigned)f2b(s[4]) | ((unsigned)f2b(s[5]) << 16);
                    o.w = (unsigned)f2b(s[6]) | ((unsigned)f2b(s[7]) << 16);
                    *(uint4*)(C + (size_t)grow * ldc + gcol) = o;
                }
            }
        } else {
            float* C = (float*)Cv;
#pragma unroll
            for (int rr = 0; rr < 4; ++rr) {
                const int idx = rr * 1024 + tid * 4;
                const int row = idx >> 7, col = idx & 127;
                const int grow = rbase + row, gcol = bn + col;
                if (grow < M && gcol + 4 <= Ncap)
                    *(float4*)(C + (size_t)grow * ldc + gcol) =
                        *(const float4*)(lbuf + row * 132 + col);
            }
        }
    }
}

// Generic 128x128 GEMM kernel with bijective XCD-chunk swizzle.
template <bool OUT_BF16>
__global__ __launch_bounds__(256, 3)
void hrr_gemm(const us16* __restrict__ A, const us16* __restrict__ B,
              void* __restrict__ C, int M, int N, int K,
              int lda, int ldb, int ldc, int Ncap, int swz) {
    __shared__ us16 smem[16384];
    int bx = blockIdx.x, by = blockIdx.y;
    if (swz) {
        const int gx = gridDim.x;
        const int id = bx + gx * by;
        const int q = (gx * gridDim.y) >> 3;
        const int nid = (id & 7) * q + (id >> 3);
        bx = nid % gx; by = nid / gx;
    }
    gemm_core<OUT_BF16>(A, B, C, M, N, K, lda, ldb, ldc, Ncap,
                        by * 128, bx * 128, smem);
}

// Fused builders: z<3 -> Mall_z(1026x1024) = Tcs @ WT_z^T (batch stride
// MROWS rows); z==3 -> MoutT(1024x1056) = WoBf @ Sfb^T. Grid (9,9,4).
__global__ __launch_bounds__(256, 3)
void hrr_gemm_builders(const us16* __restrict__ Tcs, const us16* __restrict__ WT,
                       us16* __restrict__ MallB, const us16* __restrict__ WoBf,
                       const us16* __restrict__ Sfb, us16* __restrict__ MoutB) {
    __shared__ us16 smem[16384];
    const int bm = blockIdx.y * 128, bn = blockIdx.x * 128;
    const int z = blockIdx.z;
    if (z < 3)
        gemm_core<true>(Tcs, WT + (size_t)z * D_ * D_,
                        MallB + (size_t)z * MROWS * 1024,
                        1026, 1024, 1024, 1024, 1024, 1024, 1024, bm, bn, smem);
    else
        gemm_core<true>(WoBf, Sfb, MoutB,
                        1024, KP2, 1024, 1024, 1024, KP2, KP2, bm, bn, smem);
}

// ---------------------------------------------------------------------------
// Main GEMM: Fall(4096 x LFU cols, bf16, ldc=LFP) = Xbf @ MallB^T.
// 256x256 tile, BK=64, 512 threads = 8 waves (2M x 4N). Phase-pipelined
// (T3+T4): per K-tile issue next tile's 8 global_load_lds first, then 4
// quadrant phases {snake ds_read -> setprio MFMA} split by raw s_barrier
// (loads in flight across barriers); single vmcnt(0) at tile end.
// ---------------------------------------------------------------------------
__global__ __launch_bounds__(512, 2)
void hrr_gemm_main(const us16* __restrict__ A, const us16* __restrict__ B,
                   us16* __restrict__ C) {
    __shared__ us16 smem[65536];          // 128 KB
    us16* Asb = smem;                     // [2][256*64]
    us16* Bsb = smem + 32768;

    const int tid  = threadIdx.x;
    const int lane = tid & 63;
    const int wave = tid >> 6;

    // bijective XCD-chunk swizzle over 13x16 = 208 blocks (208 % 8 == 0)
    int id = blockIdx.x + 13 * blockIdx.y;
    id = (id & 7) * 26 + (id >> 3);
    const int bx = id % 13, by = id / 13;
    const int bm = by * 256, bn = bx * 256;

    // staging source pointers: 4 row-groups for A and B (8 gl_lds per tile)
    const int srow = tid >> 3;                    // 0..63
    const int sgr  = (tid & 7) ^ (srow & 7);      // swizzled source granule
    const us16* gA[4];
    const us16* gB[4];
#pragma unroll
    for (int g = 0; g < 4; ++g) {
        int ra = bm + g * 64 + srow; if (ra > NTOK - 1) ra = NTOK - 1;
        int rb = bn + g * 64 + srow; if (rb > LFU - 1)  rb = LFU - 1;
        gA[g] = A + (size_t)ra * 1024 + sgr * 8;
        gB[g] = B + (size_t)rb * 1024 + sgr * 8;
    }

    f32x4 acc[8][4];
#pragma unroll
    for (int i = 0; i < 8; i++)
#pragma unroll
        for (int j = 0; j < 4; j++) acc[i][j] = (f32x4){0.f, 0.f, 0.f, 0.f};

    const int wmw = (wave >> 2) * 128;    // wave M-offset (2 halves)
    const int wnw = (wave & 3) * 64;      // wave N-offset (4 quarters)
    const int fr  = lane & 15;
    const int gr  = lane >> 4;            // 0..3
    const int l7  = lane & 7;

#define STAGE3(buf, ko)                                            \
    do {                                                           \
        us16* a_ = Asb + (buf) * 16384 + wave * 512;               \
        us16* b_ = Bsb + (buf) * 16384 + wave * 512;               \
        gl_lds16(gA[0] + (ko), a_);                                \
        gl_lds16(gA[1] + (ko), a_ + 4096);                         \
        gl_lds16(gA[2] + (ko), a_ + 8192);                         \
        gl_lds16(gA[3] + (ko), a_ + 12288);                        \
        gl_lds16(gB[0] + (ko), b_);                                \
        gl_lds16(gB[1] + (ko), b_ + 4096);                         \
        gl_lds16(gB[2] + (ko), b_ + 8192);                         \
        gl_lds16(gB[3] + (ko), b_ + 12288);                        \
    } while (0)

#define RBAR                                                       \
    do {                                                           \
        asm volatile("" ::: "memory");                             \
        __builtin_amdgcn_s_barrier();                              \
        asm volatile("" ::: "memory");                             \
    } while (0)

#define LOAD_A(ih)                                                              \
    do {                                                                        \
        _Pragma("unroll")                                                       \
        for (int i = 0; i < 4; ++i)                                             \
            _Pragma("unroll")                                                   \
            for (int ks = 0; ks < 2; ++ks)                                      \
                af[i][ks] = *(const bf16x8*)(Ac +                               \
                    (wmw + (ih) * 64 + i * 16 + fr) * 64 +                      \
                    (((ks << 2) | gr) ^ l7) * 8);                               \
    } while (0)

#define LOAD_B(jh)                                                              \
    do {                                                                        \
        _Pragma("unroll")                                                       \
        for (int j = 0; j < 2; ++j)                                             \
            _Pragma("unroll")                                                   \
            for (int ks = 0; ks < 2; ++ks)                                      \
                bfr[j][ks] = *(const bf16x8*)(Bc +                              \
                    (wnw + (jh) * 32 + j * 16 + fr) * 64 +                      \
                    (((ks << 2) | gr) ^ l7) * 8);                               \
    } while (0)

#define MFMA_Q(ih, jh)                                                          \
    do {                                                                        \
        __builtin_amdgcn_s_setprio(1);                                          \
        _Pragma("unroll")                                                       \
        for (int i = 0; i < 4; ++i)                                             \
            _Pragma("unroll")                                                   \
            for (int j = 0; j < 2; ++j)                                         \
                _Pragma("unroll")                                               \
                for (int ks = 0; ks < 2; ++ks)                                  \
                    acc[(ih) * 4 + i][(jh) * 2 + j] =                           \
                        __builtin_amdgcn_mfma_f32_16x16x32_bf16(                \
                            bfr[j][ks], af[i][ks],                              \
                            acc[(ih) * 4 + i][(jh) * 2 + j], 0, 0, 0);          \
        __builtin_amdgcn_s_setprio(0);                                          \
    } while (0)

    // prologue: stage tile 0, full drain
    STAGE3(0, 0);
    asm volatile("s_waitcnt vmcnt(0)" ::: "memory");
    __builtin_amdgcn_s_barrier();
    asm volatile("" ::: "memory");

    int cur = 0;
#pragma unroll 1
    for (int t = 0; t < 16; ++t) {
        if (t < 15) STAGE3(cur ^ 1, (t + 1) * 64);   // async, stays in flight

        const us16* Ac = Asb + cur * 16384;
        const us16* Bc = Bsb + cur * 16384;
        bf16x8 af[4][2], bfr[2][2];

        // snake order: (0,0) -> (0,1) -> (1,1) -> (1,0); reuse af/bf sets
        LOAD_A(0); LOAD_B(0); MFMA_Q(0, 0); RBAR;
        LOAD_B(1);            MFMA_Q(0, 1); RBAR;
        LOAD_A(1);            MFMA_Q(1, 1); RBAR;
        LOAD_B(0);            MFMA_Q(1, 0);
        asm volatile("s_waitcnt vmcnt(0)" ::: "memory");  // next tile staged
        __builtin_amdgcn_s_barrier();
        asm volatile("" ::: "memory");
        cur ^= 1;
    }
#undef STAGE3
#undef LOAD_A
#undef LOAD_B
#undef MFMA_Q
#undef RBAR

    // ---- epilogue: per-wave LDS repack -> full-line bf16 row stores ----
    __syncthreads();
    float* lw = (float*)smem + wave * (32 * 68);     // 8.7 KB per wave
    const int cl = lane & 15;
    const int rq = (lane >> 4) * 4;
#pragma unroll
    for (int p = 0; p < 4; ++p) {
#pragma unroll
        for (int ii = 0; ii < 2; ++ii) {
            const int ifr = p * 2 + ii;
#pragma unroll
            for (int j = 0; j < 4; ++j)
                *(f32x4*)(lw + (ii * 16 + cl) * 68 + j * 16 + rq) = acc[ifr][j];
        }
        __syncthreads();
#pragma unroll
        for (int rr = 0; rr < 4; ++rr) {
            const int idx = rr * 512 + lane * 8;     // 32 rows x 64 cols
            const int row = idx >> 6, col = idx & 63;
            const int grow = bm + wmw + p * 32 + row;
            const int gcol = bn + wnw + col;
            if (gcol + 8 <= LFP) {
                const float* s = lw + row * 68 + col;
                uint4 o;
                o.x = (unsigned)f2b(s[0]) | ((unsigned)f2b(s[1]) << 16);
                o.y = (unsigned)f2b(s[2]) | ((unsigned)f2b(s[3]) << 16);
                o.z = (unsigned)f2b(s[4]) | ((unsigned)f2b(s[5]) << 16);
                o.w = (unsigned)f2b(s[6]) | ((unsigned)f2b(s[7]) << 16);
                *(uint4*)(C + (size_t)grow * LFP + gcol) = o;
            }
        }
        __syncthreads();
    }
}

// ---------------------------------------------------------------------------
// Scan phase 1: chunk sums. Grid (NCH, B_, 2) f-halves, 256 threads.
// R13: aligned uint2 loads (k @ u32 514, v @ u32 1028+f0).
// ---------------------------------------------------------------------------
__global__ __launch_bounds__(256, 4)
void hrr_scan_sums(const us16* __restrict__ Fall, const int* __restrict__ perms,
                   float* __restrict__ S) {
    const int n = blockIdx.x, b = blockIdx.y, half = blockIdx.z;
    const int tid = threadIdx.x;
    const int f0 = half * 256;
    __shared__ float2 kc[F_], vc[257];

    float aR[2][C_], aI[2][C_];
    int gg[2][C_];
#pragma unroll
    for (int i = 0; i < 2; i++) {
        const int f = (i == 0) ? (f0 + tid) : 512;
        const bool act = (i == 0) || (half == 1 && tid == 0);
#pragma unroll
        for (int c = 0; c < C_; c++) {
            gg[i][c] = act ? perms[c * F_ + f] : 0;
            aR[i][c] = aI[i][c] = 0.f;
        }
    }

    for (int tl = 0; tl < TC; tl++) {
        const unsigned* row32 =
            (const unsigned*)(Fall + (size_t)(b * T_ + n * TC + tl) * LFP);
        __syncthreads();
        {
            uint2 kk = *(const uint2*)(row32 + 514 + 2 * tid);
            kc[2 * tid]     = b2f2(kk.x);
            kc[2 * tid + 1] = b2f2(kk.y);
            if (tid < 128) {
                uint2 vv = *(const uint2*)(row32 + 1028 + f0 + 2 * tid);
                vc[2 * tid]     = b2f2(vv.x);
                vc[2 * tid + 1] = b2f2(vv.y);
            }
            if (tid == 0) {
                kc[512] = b2f2(row32[1026]);
                if (half == 1) vc[256] = b2f2(row32[1540]);
            }
        }
        __syncthreads();
#pragma unroll
        for (int i = 0; i < 2; i++) {
            const int lv = (i == 0) ? tid : 256;
            if (i == 0 || (half == 1 && tid == 0)) {
                float2 v = vc[lv];
#pragma unroll
                for (int c = 0; c < C_; c++) {
                    float2 k = kc[gg[i][c]];
                    aR[i][c] += k.x * v.x - k.y * v.y;
                    aI[i][c] += k.x * v.y + k.y * v.x;
                }
            }
        }
    }
#pragma unroll
    for (int i = 0; i < 2; i++) {
        const int f = (i == 0) ? (f0 + tid) : 512;
        if (i == 0 || (half == 1 && tid == 0)) {
#pragma unroll
            for (int c = 0; c < C_; c++) {
                size_t a = ((((size_t)c * B_ + b) * NCH + n) * F_ + f) * 2;
                S[a] = aR[i][c]; S[a + 1] = aI[i][c];
            }
        }
    }
}

// ---------------------------------------------------------------------------
// Scan phase 2: exclusive prefix over chunks, per (c,b,f). 8-way unrolled.
// ---------------------------------------------------------------------------
__global__ void hrr_scan_prefix(float* __restrict__ S) {
    int tid = blockIdx.x * 256 + threadIdx.x;
    if (tid >= C_ * B_ * F_) return;
    int c = tid / (B_ * F_);
    int r = tid % (B_ * F_);
    int b = r / F_, f = r % F_;
    size_t base = (((size_t)c * B_ + b) * NCH) * F_ + f;
    float runR = 0.f, runI = 0.f;
    for (int n0 = 0; n0 < NCH; n0 += 8) {
        float tR[8], tI[8];
#pragma unroll
        for (int u = 0; u < 8; u++) {
            size_t a = (base + (size_t)(n0 + u) * F_) * 2;
            tR[u] = S[a]; tI[u] = S[a + 1];
        }
#pragma unroll
        for (int u = 0; u < 8; u++) {
            size_t a = (base + (size_t)(n0 + u) * F_) * 2;
            S[a] = runR; S[a + 1] = runI;
            runR += tR[u]; runI += tI[u];
        }
    }
}

// ---------------------------------------------------------------------------
// Scan phase 3: running kv in regs, r = mean_c kv*conj(fqp) -> Rcat.
// R13: aligned uint2 loads for q/k/v.
// ---------------------------------------------------------------------------
__global__ __launch_bounds__(256, 4)
void hrr_scan_apply(const us16* __restrict__ Fall, const int* __restrict__ perms,
                    const float* __restrict__ S, us16* __restrict__ Rcat) {
    const int n = blockIdx.x, b = blockIdx.y, half = blockIdx.z;
    const int tid = threadIdx.x;
    const int f0 = half * 256;
    __shared__ float2 qc[F_], kc[F_], vc[257];

    float kvR[2][C_], kvI[2][C_];
    int gg[2][C_];
#pragma unroll
    for (int i = 0; i < 2; i++) {
        const int f = (i == 0) ? (f0 + tid) : 512;
        const bool act = (i == 0) || (half == 1 && tid == 0);
#pragma unroll
        for (int c = 0; c < C_; c++) {
            gg[i][c] = act ? perms[c * F_ + f] : 0;
            if (act) {
                size_t a = ((((size_t)c * B_ + b) * NCH + n) * F_ + f) * 2;
                kvR[i][c] = S[a]; kvI[i][c] = S[a + 1];
            } else { kvR[i][c] = 0.f; kvI[i][c] = 0.f; }
        }
    }

    for (int tl = 0; tl < TC; tl++) {
        const int tt = b * T_ + n * TC + tl;
        const unsigned* row32 = (const unsigned*)(Fall + (size_t)tt * LFP);
        __syncthreads();
        {
            uint2 qq = *(const uint2*)(row32 + 2 * tid);
            qc[2 * tid]     = b2f2(qq.x);
            qc[2 * tid + 1] = b2f2(qq.y);
            uint2 kk = *(const uint2*)(row32 + 514 + 2 * tid);
            kc[2 * tid]     = b2f2(kk.x);
            kc[2 * tid + 1] = b2f2(kk.y);
            if (tid < 128) {
                uint2 vv = *(const uint2*)(row32 + 1028 + f0 + 2 * tid);
                vc[2 * tid]     = b2f2(vv.x);
                vc[2 * tid + 1] = b2f2(vv.y);
            }
            if (tid == 0) {
                qc[512] = b2f2(row32[512]);
                kc[512] = b2f2(row32[1026]);
                if (half == 1) vc[256] = b2f2(row32[1540]);
            }
        }
        __syncthreads();
        unsigned* out32 = (unsigned*)(Rcat + (size_t)tt * KP2);
#pragma unroll
        for (int i = 0; i < 2; i++) {
            const int f = (i == 0) ? (f0 + tid) : 512;
            const int lv = (i == 0) ? tid : 256;
            if (i == 0 || (half == 1 && tid == 0)) {
                float2 v = vc[lv];
                float accR = 0.f, accI = 0.f;
#pragma unroll
                for (int c = 0; c < C_; c++) {
                    int g = gg[i][c];
                    float2 k = kc[g];
                    float nR = kvR[i][c] + k.x * v.x - k.y * v.y;
                    float nI = kvI[i][c] + k.x * v.y + k.y * v.x;
                    kvR[i][c] = nR; kvI[i][c] = nI;
                    float2 q = qc[g];
                    accR += nR * q.x + nI * q.y;
                    accI += nI * q.x - nR * q.y;
                }
                out32[f] = (unsigned)f2b(accR * 0.1f)
                         | ((unsigned)f2b(accI * 0.1f) << 16);
            }
        }
        if (half == 0 && tid < 15)                  // zero pad cols 1026..1055
            out32[513 + tid] = 0;
    }
}

// ---------------------------------------------------------------------------
extern "C" void kernel_launch(void* const* d_in, const int* in_sizes, int n_in,
                              void* d_out, int out_size, void* d_ws, size_t ws_size,
                              hipStream_t stream) {
    const float* x  = (const float*)d_in[0];
    const float* Wq = (const float*)d_in[1];
    const float* Wk = (const float*)d_in[2];
    const float* Wv = (const float*)d_in[3];
    const float* Wo = (const float*)d_in[4];
    const int* perms = (const int*)d_in[5];
    float* out = (float*)d_out;

    char* ws = (char*)d_ws;
    us16* Xbf   = (us16*)(ws + O_XBF);
    us16* WT    = (us16*)(ws + O_WT);
    us16* WoBf  = (us16*)(ws + O_WOBF);
    us16* Tcs   = (us16*)(ws + O_TCS);
    us16* Sfb   = (us16*)(ws + O_SFB);
    us16* MallB = (us16*)(ws + O_MALLB);
    us16* MoutB = (us16*)(ws + O_MOUTB);
    us16* Rcat  = (us16*)(ws + O_RCAT);
    us16* Fall  = (us16*)(ws + O_FALL);
    float* Ssc  = (float*)(ws + O_SSCAN);

    // fused prep: all 5 independent small kernels in one dispatch
    hrr_prep<<<16520, 256, 0, stream>>>(x, Wq, Wk, Wv, Wo, Xbf, WT, WoBf, Tcs, Sfb);

    // fused builders: Mall x3 (batch stride MROWS) + MoutT, one dispatch
    hrr_gemm_builders<<<dim3(9, 9, 4), 256, 0, stream>>>(Tcs, WT, MallB, WoBf, Sfb, MoutB);

    // main GEMM: 256x256 phase-pipelined kernel, grid 13x16 = 208 blocks
    hrr_gemm_main<<<dim3(13, 16), 512, 0, stream>>>(Xbf, MallB, Fall);

    // chunked causal scan (NCH=256 chunks, TC=8)
    hrr_scan_sums<<<dim3(NCH, B_, 2), 256, 0, stream>>>(Fall, perms, Ssc);
    hrr_scan_prefix<<<(C_ * B_ * F_ + 255) / 256, 256, 0, stream>>>(Ssc);
    hrr_scan_apply<<<dim3(NCH, B_, 2), 256, 0, stream>>>(Fall, perms, Ssc, Rcat);

    // output GEMM: out(4096x1024 fp32) = Rcat(4096x1056) @ MoutB^T (128x128 core)
    hrr_gemm<false><<<dim3(8, 32), 256, 0, stream>>>(
        Rcat, MoutB, out, NTOK, D_, KP2, KP2, KP2, D_, D_, 1);
}

// Round 10
// 217.216 us; speedup vs baseline: 1.1434x; 1.1434x over previous
//
#include <hip/hip_runtime.h>
#include <math.h>

// Problem constants
#define B_   2
#define T_   2048
#define D_   1024
#define C_   10
#define F_   513
#define NTOK (B_ * T_)     // 4096 rows
#define LF   3078          // Fall logical cols: [q(1026) | k(1026) | v(1026)] interleaved re/im
#define LFP  3136          // Fall row stride (us16): 6272 B, line-aligned rows
#define KP2  1056          // padded K for output GEMM (cols 0..1025 used, pad 30)
#define NCH  128           // scan chunks (R8 proven; 256 regressed in R9)
#define TC   (T_ / NCH)    // 16 timesteps per chunk

typedef unsigned short us16;
typedef __attribute__((ext_vector_type(8))) __bf16 bf16x8;
typedef __attribute__((ext_vector_type(4))) float  f32x4;

// Workspace layout (bytes). RCAT aliases PREP (WT+WoBf+Tcs, 10.49 MB >=
// 8.65 MB needed; all builders finish before scan_apply writes).
#define O_XBF    ((size_t)0)                 // x bf16: 8,388,608
#define O_PREP   ((size_t)8388608)
#define O_WT     (O_PREP)                    // WT bf16 3x1024x1024: 6,291,456
#define O_WOBF   (O_PREP + 6291456)          // Wo bf16: 2,097,152
#define O_TCS    (O_PREP + 8388608)          // Tcs bf16 1026x1024: 2,101,248
#define O_RCAT   (O_PREP)                    // Rcat bf16 4096x1056: 8,650,752
#define O_SFB    (O_PREP + 10489856)         // Sfb bf16 1056x1024: 2,162,688
#define O_MALLB  (O_SFB + 2162688)           // Mall bf16 3x1026x1024: 6,303,744
#define O_MOUTB  (O_MALLB + 6303744)         // MoutT bf16 1024x1056: 2,162,688
#define O_FALL   (O_MOUTB + 2162688)         // Fall bf16 4096x3136: 25,690,112
#define O_SSCAN  (O_FALL + 25690112)         // scan sums fp32: 10,506,240

__device__ __forceinline__ us16 f2b(float f) {
    union { float f; unsigned u; } v; v.f = f;
    unsigned r = v.u + 0x7FFFu + ((v.u >> 16) & 1u);
    return (us16)(r >> 16);
}

// packed bf16 pair -> float2 (bit-exact)
__device__ __forceinline__ float2 b2f2(unsigned w) {
    union { unsigned u; float f; } a, b;
    a.u = (w & 0xffffu) << 16;
    b.u = w & 0xffff0000u;
    return make_float2(a.f, b.f);
}

// async global->LDS DMA, 16 B per lane. LDS dest is wave-uniform base +
// lane*16 (HW-fixed); global src is per-lane.
__device__ __forceinline__ void gl_lds16(const us16* g, us16* l) {
    __builtin_amdgcn_global_load_lds(
        (const __attribute__((address_space(1))) unsigned*)g,
        (__attribute__((address_space(3))) unsigned*)l, 16, 0, 0);
}

// ---------------------------------------------------------------------------
// Fused prep: x->bf16 | Wo->bf16 | W transpose x3 | Tcs | Sfb, one dispatch,
// 1D grid partitioned by block-id range (branch is block-uniform).
// ---------------------------------------------------------------------------
__global__ __launch_bounds__(256)
void hrr_prep(const float* __restrict__ x,  const float* __restrict__ Wq,
              const float* __restrict__ Wk, const float* __restrict__ Wv,
              const float* __restrict__ Wo,
              us16* __restrict__ Xbf, us16* __restrict__ WT,
              us16* __restrict__ WoBf, us16* __restrict__ Tcs,
              us16* __restrict__ Sfb) {
    __shared__ float t[32][33];
    const int bid = blockIdx.x, tid = threadIdx.x;
    if (bid < 4096) {
        int i = bid * 256 + tid;
        float4 v = ((const float4*)x)[i];
        ushort4 o;
        o.x = f2b(v.x); o.y = f2b(v.y); o.z = f2b(v.z); o.w = f2b(v.w);
        ((ushort4*)Xbf)[i] = o;
    } else if (bid < 5120) {
        int i = (bid - 4096) * 256 + tid;
        float4 v = ((const float4*)Wo)[i];
        ushort4 o;
        o.x = f2b(v.x); o.y = f2b(v.y); o.z = f2b(v.z); o.w = f2b(v.w);
        ((ushort4*)WoBf)[i] = o;
    } else if (bid < 8192) {
        const int l  = bid - 5120;
        const int bz = l >> 10, l2 = l & 1023;
        const int bx = (l2 & 31) * 32, by = (l2 >> 5) * 32;
        const float* W = (bz == 0) ? Wq : (bz == 1) ? Wk : Wv;
        us16* O = WT + (size_t)bz * D_ * D_;
        const int tx = tid & 31, ty = tid >> 5;   // 32 x 8
#pragma unroll
        for (int i = 0; i < 32; i += 8)
            t[ty + i][tx] = W[(size_t)(by + ty + i) * D_ + bx + tx];
        __syncthreads();
#pragma unroll
        for (int i = 0; i < 32; i += 8)
            O[(size_t)(bx + ty + i) * D_ + by + tx] = f2b(t[tx][ty + i]);
    } else if (bid < 12296) {
        // Tcs rows interleaved: row 2f = cos(2*pi*f*e/1024), 2f+1 = -sin
        int idx = (bid - 8192) * 256 + tid;
        int r = idx >> 10, e = idx & 1023;
        int f = r >> 1;
        float ang = (float)((f * e) & 1023) * 6.135923151542565e-3f;
        Tcs[idx] = f2b((r & 1) ? -sinf(ang) : cosf(ang));
    } else {
        // Sfb rows interleaved: 2f = s_f*cos, 2f+1 = -s_f*sin; pad rows 0
        int idx = (bid - 12296) * 256 + tid;
        int r = idx >> 10, e = idx & 1023;
        float v = 0.f;
        if (r < 1026) {
            int f = r >> 1;
            float s = (f == 0 || f == 512) ? (1.0f / 1024.0f) : (2.0f / 1024.0f);
            float ang = (float)((f * e) & 1023) * 6.135923151542565e-3f;
            v = (r & 1) ? -s * sinf(ang) : s * cosf(ang);
        }
        Sfb[idx] = f2b(v);
    }
}

// ---------------------------------------------------------------------------
// 128x128 bf16 MFMA GEMM core: C = A @ B^T. 2-buf, ONE barrier per K-step,
// gload_lds staging, granule XOR-swizzle (0 bank conflicts). Swapped mfma
// operands + LDS repack -> full-line row stores. Builders + output GEMM.
// ---------------------------------------------------------------------------
template <bool OUT_BF16>
__device__ __forceinline__ void gemm_core(
    const us16* __restrict__ A, const us16* __restrict__ B, void* __restrict__ Cv,
    int M, int N, int K, int lda, int ldb, int ldc, int Ncap,
    int bm, int bn, us16* smem) {
    us16* As = smem;
    us16* Bs = smem + 8192;

    const int tid  = threadIdx.x;
    const int lane = tid & 63;
    const int wave = tid >> 6;
    const int wm = (wave >> 1) * 64;
    const int wn = (wave & 1) * 64;

    const int r0    = tid >> 2;
    const int g_lds = tid & 3;
    const int g_src = g_lds ^ ((r0 >> 1) & 3);
    const int c4    = g_src * 8;

    int rA0 = bm + r0;      if (rA0 >= M) rA0 = M - 1;
    int rA1 = bm + 64 + r0; if (rA1 >= M) rA1 = M - 1;
    int rB0 = bn + r0;      if (rB0 >= N) rB0 = N - 1;
    int rB1 = bn + 64 + r0; if (rB1 >= N) rB1 = N - 1;
    const us16* pA0 = A + (size_t)rA0 * lda + c4;
    const us16* pA1 = A + (size_t)rA1 * lda + c4;
    const us16* pB0 = B + (size_t)rB0 * ldb + c4;
    const us16* pB1 = B + (size_t)rB1 * ldb + c4;

    f32x4 acc[4][4];
#pragma unroll
    for (int i = 0; i < 4; i++)
#pragma unroll
        for (int j = 0; j < 4; j++) acc[i][j] = (f32x4){0.f, 0.f, 0.f, 0.f};

    const int fr = lane & 15;
    const int gq = ((lane >> 4) ^ ((fr >> 1) & 3)) * 8;

    const int wb = wave * 512;
#define STAGE_TILE(buf, ko)                                  \
    do {                                                     \
        us16* a_ = As + (buf) * 4096 + wb;                   \
        us16* b_ = Bs + (buf) * 4096 + wb;                   \
        gl_lds16(pA0 + (ko), a_);                            \
        gl_lds16(pA1 + (ko), a_ + 2048);                     \
        gl_lds16(pB0 + (ko), b_);                            \
        gl_lds16(pB1 + (ko), b_ + 2048);                     \
    } while (0)

    STAGE_TILE(0, 0);
    __syncthreads();

    int cur = 0;
    for (int k0 = 0; k0 < K; k0 += 32) {
        const int kn = k0 + 32;
        if (kn < K) STAGE_TILE(cur ^ 1, kn);

        const us16* Ac = As + cur * 4096;
        const us16* Bc = Bs + cur * 4096;
        bf16x8 af[4], bfr[4];
#pragma unroll
        for (int i = 0; i < 4; i++)
            af[i] = *(const bf16x8*)(Ac + (wm + i * 16 + fr) * 32 + gq);
#pragma unroll
        for (int j = 0; j < 4; j++)
            bfr[j] = *(const bf16x8*)(Bc + (wn + j * 16 + fr) * 32 + gq);
#pragma unroll
        for (int i = 0; i < 4; i++)
#pragma unroll
            for (int j = 0; j < 4; j++)
                acc[i][j] = __builtin_amdgcn_mfma_f32_16x16x32_bf16(bfr[j], af[i], acc[i][j], 0, 0, 0);

        __syncthreads();
        cur ^= 1;
    }
#undef STAGE_TILE

    const int cl  = lane & 15;
    const int rq  = (lane >> 4) * 4;
    float* lbuf = (float*)smem;
#pragma unroll
    for (int p = 0; p < 4; ++p) {
        __syncthreads();
        if ((wave >> 1) == (p >> 1)) {
            const int ib = (p & 1) * 2;
#pragma unroll
            for (int ii = 0; ii < 2; ++ii) {
                const int rl = ii * 16 + cl;
#pragma unroll
                for (int j = 0; j < 4; ++j)
                    *(f32x4*)(lbuf + rl * 132 + wn + j * 16 + rq) = acc[ib + ii][j];
            }
        }
        __syncthreads();
        const int rbase = bm + p * 32;
        if (OUT_BF16) {
            us16* C = (us16*)Cv;
#pragma unroll
            for (int rr = 0; rr < 2; ++rr) {
                const int idx = rr * 2048 + tid * 8;
                const int row = idx >> 7, col = idx & 127;
                const int grow = rbase + row, gcol = bn + col;
                if (grow < M && gcol + 8 <= Ncap) {
                    const float* s = lbuf + row * 132 + col;
                    uint4 o;
                    o.x = (unsigned)f2b(s[0]) | ((unsigned)f2b(s[1]) << 16);
                    o.y = (unsigned)f2b(s[2]) | ((unsigned)f2b(s[3]) << 16);
                    o.z = (unsigned)f2b(s[4]) | ((unsigned)f2b(s[5]) << 16);
                    o.w = (unsigned)f2b(s[6]) | ((unsigned)f2b(s[7]) << 16);
                    *(uint4*)(C + (size_t)grow * ldc + gcol) = o;
                }
            }
        } else {
            float* C = (float*)Cv;
#pragma unroll
            for (int rr = 0; rr < 4; ++rr) {
                const int idx = rr * 1024 + tid * 4;
                const int row = idx >> 7, col = idx & 127;
                const int grow = rbase + row, gcol = bn + col;
                if (grow < M && gcol + 4 <= Ncap)
                    *(float4*)(C + (size_t)grow * ldc + gcol) =
                        *(const float4*)(lbuf + row * 132 + col);
            }
        }
    }
}

// Generic 128x128 GEMM kernel with bijective XCD-chunk swizzle.
template <bool OUT_BF16>
__global__ __launch_bounds__(256, 3)
void hrr_gemm(const us16* __restrict__ A, const us16* __restrict__ B,
              void* __restrict__ C, int M, int N, int K,
              int lda, int ldb, int ldc, int Ncap, int swz) {
    __shared__ us16 smem[16384];
    int bx = blockIdx.x, by = blockIdx.y;
    if (swz) {
        const int gx = gridDim.x;
        const int id = bx + gx * by;
        const int q = (gx * gridDim.y) >> 3;
        const int nid = (id & 7) * q + (id >> 3);
        bx = nid % gx; by = nid / gx;
    }
    gemm_core<OUT_BF16>(A, B, C, M, N, K, lda, ldb, ldc, Ncap,
                        by * 128, bx * 128, smem);
}

// Fused builders: z<3 -> Mall_z(1026x1024) = Tcs @ WT_z^T;
// z==3 -> MoutT(1024x1056) = WoBf @ Sfb^T. Grid (9,9,4), 128x128 tiles.
__global__ __launch_bounds__(256, 3)
void hrr_gemm_builders(const us16* __restrict__ Tcs, const us16* __restrict__ WT,
                       us16* __restrict__ MallB, const us16* __restrict__ WoBf,
                       const us16* __restrict__ Sfb, us16* __restrict__ MoutB) {
    __shared__ us16 smem[16384];
    const int bm = blockIdx.y * 128, bn = blockIdx.x * 128;
    const int z = blockIdx.z;
    if (z < 3)
        gemm_core<true>(Tcs, WT + (size_t)z * D_ * D_,
                        MallB + (size_t)z * 1026 * 1024,
                        1026, 1024, 1024, 1024, 1024, 1024, 1024, bm, bn, smem);
    else
        gemm_core<true>(WoBf, Sfb, MoutB,
                        1024, KP2, 1024, 1024, 1024, KP2, KP2, bm, bn, smem);
}

// ---------------------------------------------------------------------------
// Main GEMM: Fall(4096 x 3078 cols used, bf16, ldc=LFP) = Xbf @ MallB^T.
// 256x256 tile, BK=64, 512 threads = 8 waves (2M x 4N). Phase-pipelined
// (T3+T4): per K-tile issue next tile's 8 global_load_lds first, then 4
// quadrant phases {snake ds_read -> setprio MFMA} split by raw s_barrier
// (loads in flight across barriers); single vmcnt(0) at tile end.
// ---------------------------------------------------------------------------
__global__ __launch_bounds__(512, 2)
void hrr_gemm_main(const us16* __restrict__ A, const us16* __restrict__ B,
                   us16* __restrict__ C) {
    __shared__ us16 smem[65536];          // 128 KB
    us16* Asb = smem;                     // [2][256*64]
    us16* Bsb = smem + 32768;

    const int tid  = threadIdx.x;
    const int lane = tid & 63;
    const int wave = tid >> 6;

    // bijective XCD-chunk swizzle over 13x16 = 208 blocks (208 % 8 == 0)
    int id = blockIdx.x + 13 * blockIdx.y;
    id = (id & 7) * 26 + (id >> 3);
    const int bx = id % 13, by = id / 13;
    const int bm = by * 256, bn = bx * 256;

    // staging source pointers: 4 row-groups for A and B (8 gl_lds per tile)
    const int srow = tid >> 3;                    // 0..63
    const int sgr  = (tid & 7) ^ (srow & 7);      // swizzled source granule
    const us16* gA[4];
    const us16* gB[4];
#pragma unroll
    for (int g = 0; g < 4; ++g) {
        int ra = bm + g * 64 + srow; if (ra > NTOK - 1) ra = NTOK - 1;
        int rb = bn + g * 64 + srow; if (rb > LF - 1)   rb = LF - 1;
        gA[g] = A + (size_t)ra * 1024 + sgr * 8;
        gB[g] = B + (size_t)rb * 1024 + sgr * 8;
    }

    f32x4 acc[8][4];
#pragma unroll
    for (int i = 0; i < 8; i++)
#pragma unroll
        for (int j = 0; j < 4; j++) acc[i][j] = (f32x4){0.f, 0.f, 0.f, 0.f};

    const int wmw = (wave >> 2) * 128;    // wave M-offset (2 halves)
    const int wnw = (wave & 3) * 64;      // wave N-offset (4 quarters)
    const int fr  = lane & 15;
    const int gr  = lane >> 4;            // 0..3
    const int l7  = lane & 7;

#define STAGE3(buf, ko)                                            \
    do {                                                           \
        us16* a_ = Asb + (buf) * 16384 + wave * 512;               \
        us16* b_ = Bsb + (buf) * 16384 + wave * 512;               \
        gl_lds16(gA[0] + (ko), a_);                                \
        gl_lds16(gA[1] + (ko), a_ + 4096);                         \
        gl_lds16(gA[2] + (ko), a_ + 8192);                         \
        gl_lds16(gA[3] + (ko), a_ + 12288);                        \
        gl_lds16(gB[0] + (ko), b_);                                \
        gl_lds16(gB[1] + (ko), b_ + 4096);                         \
        gl_lds16(gB[2] + (ko), b_ + 8192);                         \
        gl_lds16(gB[3] + (ko), b_ + 12288);                        \
    } while (0)

#define RBAR                                                       \
    do {                                                           \
        asm volatile("" ::: "memory");                             \
        __builtin_amdgcn_s_barrier();                              \
        asm volatile("" ::: "memory");                             \
    } while (0)

#define LOAD_A(ih)                                                              \
    do {                                                                        \
        _Pragma("unroll")                                                       \
        for (int i = 0; i < 4; ++i)                                             \
            _Pragma("unroll")                                                   \
            for (int ks = 0; ks < 2; ++ks)                                      \
                af[i][ks] = *(const bf16x8*)(Ac +                               \
                    (wmw + (ih) * 64 + i * 16 + fr) * 64 +                      \
                    (((ks << 2) | gr) ^ l7) * 8);                               \
    } while (0)

#define LOAD_B(jh)                                                              \
    do {                                                                        \
        _Pragma("unroll")                                                       \
        for (int j = 0; j < 2; ++j)                                             \
            _Pragma("unroll")                                                   \
            for (int ks = 0; ks < 2; ++ks)                                      \
                bfr[j][ks] = *(const bf16x8*)(Bc +                              \
                    (wnw + (jh) * 32 + j * 16 + fr) * 64 +                      \
                    (((ks << 2) | gr) ^ l7) * 8);                               \
    } while (0)

#define MFMA_Q(ih, jh)                                                          \
    do {                                                                        \
        __builtin_amdgcn_s_setprio(1);                                          \
        _Pragma("unroll")                                                       \
        for (int i = 0; i < 4; ++i)                                             \
            _Pragma("unroll")                                                   \
            for (int j = 0; j < 2; ++j)                                         \
                _Pragma("unroll")                                               \
                for (int ks = 0; ks < 2; ++ks)                                  \
                    acc[(ih) * 4 + i][(jh) * 2 + j] =                           \
                        __builtin_amdgcn_mfma_f32_16x16x32_bf16(                \
                            bfr[j][ks], af[i][ks],                              \
                            acc[(ih) * 4 + i][(jh) * 2 + j], 0, 0, 0);          \
        __builtin_amdgcn_s_setprio(0);                                          \
    } while (0)

    // prologue: stage tile 0, full drain
    STAGE3(0, 0);
    asm volatile("s_waitcnt vmcnt(0)" ::: "memory");
    __builtin_amdgcn_s_barrier();
    asm volatile("" ::: "memory");

    int cur = 0;
#pragma unroll 1
    for (int t = 0; t < 16; ++t) {
        if (t < 15) STAGE3(cur ^ 1, (t + 1) * 64);   // async, stays in flight

        const us16* Ac = Asb + cur * 16384;
        const us16* Bc = Bsb + cur * 16384;
        bf16x8 af[4][2], bfr[2][2];

        // snake order: (0,0) -> (0,1) -> (1,1) -> (1,0); reuse af/bf sets
        LOAD_A(0); LOAD_B(0); MFMA_Q(0, 0); RBAR;
        LOAD_B(1);            MFMA_Q(0, 1); RBAR;
        LOAD_A(1);            MFMA_Q(1, 1); RBAR;
        LOAD_B(0);            MFMA_Q(1, 0);
        asm volatile("s_waitcnt vmcnt(0)" ::: "memory");  // next tile staged
        __builtin_amdgcn_s_barrier();
        asm volatile("" ::: "memory");
        cur ^= 1;
    }
#undef STAGE3
#undef LOAD_A
#undef LOAD_B
#undef MFMA_Q
#undef RBAR

    // ---- epilogue: per-wave LDS repack -> full-line bf16 row stores ----
    __syncthreads();
    float* lw = (float*)smem + wave * (32 * 68);     // 8.7 KB per wave
    const int cl = lane & 15;
    const int rq = (lane >> 4) * 4;
#pragma unroll
    for (int p = 0; p < 4; ++p) {
#pragma unroll
        for (int ii = 0; ii < 2; ++ii) {
            const int ifr = p * 2 + ii;
#pragma unroll
            for (int j = 0; j < 4; ++j)
                *(f32x4*)(lw + (ii * 16 + cl) * 68 + j * 16 + rq) = acc[ifr][j];
        }
        __syncthreads();
#pragma unroll
        for (int rr = 0; rr < 4; ++rr) {
            const int idx = rr * 512 + lane * 8;     // 32 rows x 64 cols
            const int row = idx >> 6, col = idx & 63;
            const int grow = bm + wmw + p * 32 + row;
            const int gcol = bn + wnw + col;
            if (gcol + 8 <= LFP) {
                const float* s = lw + row * 68 + col;
                uint4 o;
                o.x = (unsigned)f2b(s[0]) | ((unsigned)f2b(s[1]) << 16);
                o.y = (unsigned)f2b(s[2]) | ((unsigned)f2b(s[3]) << 16);
                o.z = (unsigned)f2b(s[4]) | ((unsigned)f2b(s[5]) << 16);
                o.w = (unsigned)f2b(s[6]) | ((unsigned)f2b(s[7]) << 16);
                *(uint4*)(C + (size_t)grow * LFP + gcol) = o;
            }
        }
        __syncthreads();
    }
}

// ---------------------------------------------------------------------------
// Scan phase 1: chunk sums. Grid (NCH, B_, 2) f-halves, 256 threads.
// R14: T14 issue-early prefetch — next row's k/v loaded into regs right
// after the LDS-write barrier; the compute phase + barrier hides the load
// latency (vmcnt wait deferred to next iter's LDS write).
// Fall u32 layout per row (R32=1568): q@0, k@513, v@1026.
// ---------------------------------------------------------------------------
__global__ __launch_bounds__(256, 4)
void hrr_scan_sums(const us16* __restrict__ Fall, const int* __restrict__ perms,
                   float* __restrict__ S) {
    const int n = blockIdx.x, b = blockIdx.y, half = blockIdx.z;
    const int tid = threadIdx.x;
    const int f0 = half * 256;
    __shared__ float2 kc[F_], vc[257];

    float aR[2][C_], aI[2][C_];
    int gg[2][C_];
#pragma unroll
    for (int i = 0; i < 2; i++) {
        const int f = (i == 0) ? (f0 + tid) : 512;
        const bool act = (i == 0) || (half == 1 && tid == 0);
#pragma unroll
        for (int c = 0; c < C_; c++) {
            gg[i][c] = act ? perms[c * F_ + f] : 0;
            aR[i][c] = aI[i][c] = 0.f;
        }
    }

    const unsigned* rowb =
        (const unsigned*)(Fall + (size_t)(b * T_ + n * TC) * LFP);
    const int R32 = LFP / 2;            // 1568 u32 per row

    unsigned rk0, rk1, rk2 = 0, rv0, rv1 = 0;
#define SFETCH(tl)                                                   \
    do {                                                             \
        const unsigned* r_ = rowb + (size_t)(tl) * R32;              \
        rk0 = r_[513 + tid];                                         \
        rk1 = r_[769 + tid];                                         \
        rv0 = r_[1026 + f0 + tid];                                   \
        if (tid == 0) { rk2 = r_[1025]; rv1 = r_[1538]; }            \
    } while (0)

    SFETCH(0);
    for (int tl = 0; tl < TC; tl++) {
        __syncthreads();                 // prev iter's LDS consumers done
        kc[tid]       = b2f2(rk0);
        kc[256 + tid] = b2f2(rk1);
        vc[tid]       = b2f2(rv0);
        if (tid == 0) { kc[512] = b2f2(rk2); if (half) vc[256] = b2f2(rv1); }
        __syncthreads();
        if (tl + 1 < TC) SFETCH(tl + 1); // issue next row early (async)
#pragma unroll
        for (int i = 0; i < 2; i++) {
            const int lv = (i == 0) ? tid : 256;
            if (i == 0 || (half == 1 && tid == 0)) {
                float2 v = vc[lv];
#pragma unroll
                for (int c = 0; c < C_; c++) {
                    float2 k = kc[gg[i][c]];
                    aR[i][c] += k.x * v.x - k.y * v.y;
                    aI[i][c] += k.x * v.y + k.y * v.x;
                }
            }
        }
    }
#undef SFETCH
#pragma unroll
    for (int i = 0; i < 2; i++) {
        const int f = (i == 0) ? (f0 + tid) : 512;
        if (i == 0 || (half == 1 && tid == 0)) {
#pragma unroll
            for (int c = 0; c < C_; c++) {
                size_t a = ((((size_t)c * B_ + b) * NCH + n) * F_ + f) * 2;
                S[a] = aR[i][c]; S[a + 1] = aI[i][c];
            }
        }
    }
}

// ---------------------------------------------------------------------------
// Scan phase 2: exclusive prefix over chunks, per (c,b,f). 8-way unrolled.
// ---------------------------------------------------------------------------
__global__ void hrr_scan_prefix(float* __restrict__ S) {
    int tid = blockIdx.x * 256 + threadIdx.x;
    if (tid >= C_ * B_ * F_) return;
    int c = tid / (B_ * F_);
    int r = tid % (B_ * F_);
    int b = r / F_, f = r % F_;
    size_t base = (((size_t)c * B_ + b) * NCH) * F_ + f;
    float runR = 0.f, runI = 0.f;
    for (int n0 = 0; n0 < NCH; n0 += 8) {
        float tR[8], tI[8];
#pragma unroll
        for (int u = 0; u < 8; u++) {
            size_t a = (base + (size_t)(n0 + u) * F_) * 2;
            tR[u] = S[a]; tI[u] = S[a + 1];
        }
#pragma unroll
        for (int u = 0; u < 8; u++) {
            size_t a = (base + (size_t)(n0 + u) * F_) * 2;
            S[a] = runR; S[a + 1] = runI;
            runR += tR[u]; runI += tI[u];
        }
    }
}

// ---------------------------------------------------------------------------
// Scan phase 3: running kv in regs, r = mean_c kv*conj(fqp) -> Rcat.
// R14: T14 issue-early prefetch of next row's q/k/v (same pattern as sums).
// ---------------------------------------------------------------------------
__global__ __launch_bounds__(256, 4)
void hrr_scan_apply(const us16* __restrict__ Fall, const int* __restrict__ perms,
                    const float* __restrict__ S, us16* __restrict__ Rcat) {
    const int n = blockIdx.x, b = blockIdx.y, half = blockIdx.z;
    const int tid = threadIdx.x;
    const int f0 = half * 256;
    __shared__ float2 qc[F_], kc[F_], vc[257];

    float kvR[2][C_], kvI[2][C_];
    int gg[2][C_];
#pragma unroll
    for (int i = 0; i < 2; i++) {
        const int f = (i == 0) ? (f0 + tid) : 512;
        const bool act = (i == 0) || (half == 1 && tid == 0);
#pragma unroll
        for (int c = 0; c < C_; c++) {
            gg[i][c] = act ? perms[c * F_ + f] : 0;
            if (act) {
                size_t a = ((((size_t)c * B_ + b) * NCH + n) * F_ + f) * 2;
                kvR[i][c] = S[a]; kvI[i][c] = S[a + 1];
            } else { kvR[i][c] = 0.f; kvI[i][c] = 0.f; }
        }
    }

    const unsigned* rowb =
        (const unsigned*)(Fall + (size_t)(b * T_ + n * TC) * LFP);
    const int R32 = LFP / 2;            // 1568 u32 per row

    unsigned rq0, rq1, rq2 = 0, rk0, rk1, rk2 = 0, rv0, rv1 = 0;
#define AFETCH(tl)                                                   \
    do {                                                             \
        const unsigned* r_ = rowb + (size_t)(tl) * R32;              \
        rq0 = r_[tid];       rq1 = r_[256 + tid];                    \
        rk0 = r_[513 + tid]; rk1 = r_[769 + tid];                    \
        rv0 = r_[1026 + f0 + tid];                                   \
        if (tid == 0) { rq2 = r_[512]; rk2 = r_[1025]; rv1 = r_[1538]; } \
    } while (0)

    AFETCH(0);
    for (int tl = 0; tl < TC; tl++) {
        const int tt = b * T_ + n * TC + tl;
        __syncthreads();                 // prev iter's LDS consumers done
        qc[tid]       = b2f2(rq0);
        qc[256 + tid] = b2f2(rq1);
        kc[tid]       = b2f2(rk0);
        kc[256 + tid] = b2f2(rk1);
        vc[tid]       = b2f2(rv0);
        if (tid == 0) {
            qc[512] = b2f2(rq2); kc[512] = b2f2(rk2);
            if (half) vc[256] = b2f2(rv1);
        }
        __syncthreads();
        if (tl + 1 < TC) AFETCH(tl + 1); // issue next row early (async)
        unsigned* out32 = (unsigned*)(Rcat + (size_t)tt * KP2);
#pragma unroll
        for (int i = 0; i < 2; i++) {
            const int f = (i == 0) ? (f0 + tid) : 512;
            const int lv = (i == 0) ? tid : 256;
            if (i == 0 || (half == 1 && tid == 0)) {
                float2 v = vc[lv];
                float accR = 0.f, accI = 0.f;
#pragma unroll
                for (int c = 0; c < C_; c++) {
                    int g = gg[i][c];
                    float2 k = kc[g];
                    float nR = kvR[i][c] + k.x * v.x - k.y * v.y;
                    float nI = kvI[i][c] + k.x * v.y + k.y * v.x;
                    kvR[i][c] = nR; kvI[i][c] = nI;
                    float2 q = qc[g];
                    accR += nR * q.x + nI * q.y;
                    accI += nI * q.x - nR * q.y;
                }
                out32[f] = (unsigned)f2b(accR * 0.1f)
                         | ((unsigned)f2b(accI * 0.1f) << 16);
            }
        }
        if (half == 0 && tid < 15)                  // zero pad cols 1026..1055
            out32[513 + tid] = 0;
    }
#undef AFETCH
}

// ---------------------------------------------------------------------------
extern "C" void kernel_launch(void* const* d_in, const int* in_sizes, int n_in,
                              void* d_out, int out_size, void* d_ws, size_t ws_size,
                              hipStream_t stream) {
    const float* x  = (const float*)d_in[0];
    const float* Wq = (const float*)d_in[1];
    const float* Wk = (const float*)d_in[2];
    const float* Wv = (const float*)d_in[3];
    const float* Wo = (const float*)d_in[4];
    const int* perms = (const int*)d_in[5];
    float* out = (float*)d_out;

    char* ws = (char*)d_ws;
    us16* Xbf   = (us16*)(ws + O_XBF);
    us16* WT    = (us16*)(ws + O_WT);
    us16* WoBf  = (us16*)(ws + O_WOBF);
    us16* Tcs   = (us16*)(ws + O_TCS);
    us16* Sfb   = (us16*)(ws + O_SFB);
    us16* MallB = (us16*)(ws + O_MALLB);
    us16* MoutB = (us16*)(ws + O_MOUTB);
    us16* Rcat  = (us16*)(ws + O_RCAT);
    us16* Fall  = (us16*)(ws + O_FALL);
    float* Ssc  = (float*)(ws + O_SSCAN);

    // fused prep: all 5 independent small kernels in one dispatch
    hrr_prep<<<16520, 256, 0, stream>>>(x, Wq, Wk, Wv, Wo, Xbf, WT, WoBf, Tcs, Sfb);

    // fused builders: Mall x3 + MoutT, one dispatch (128x128 core)
    hrr_gemm_builders<<<dim3(9, 9, 4), 256, 0, stream>>>(Tcs, WT, MallB, WoBf, Sfb, MoutB);

    // main GEMM: 256x256 phase-pipelined kernel, grid 13x16 = 208 blocks
    hrr_gemm_main<<<dim3(13, 16), 512, 0, stream>>>(Xbf, MallB, Fall);

    // chunked causal scan (NCH=128, TC=16; scan kernels T14-prefetched)
    hrr_scan_sums<<<dim3(NCH, B_, 2), 256, 0, stream>>>(Fall, perms, Ssc);
    hrr_scan_prefix<<<(C_ * B_ * F_ + 255) / 256, 256, 0, stream>>>(Ssc);
    hrr_scan_apply<<<dim3(NCH, B_, 2), 256, 0, stream>>>(Fall, perms, Ssc, Rcat);

    // output GEMM: out(4096x1024 fp32) = Rcat(4096x1056) @ MoutB^T (128x128 core)
    hrr_gemm<false><<<dim3(8, 32), 256, 0, stream>>>(
        Rcat, MoutB, out, NTOK, D_, KP2, KP2, KP2, D_, D_, 1);
}

// Round 11
// 214.532 us; speedup vs baseline: 1.1577x; 1.0125x over previous
//
#include <hip/hip_runtime.h>
#include <math.h>

// Problem constants
#define B_   2
#define T_   2048
#define D_   1024
#define C_   10
#define F_   513
#define NTOK (B_ * T_)     // 4096 rows
#define LF   3078          // Fall logical cols: [q(1026) | k(1026) | v(1026)] interleaved re/im
#define LFP  3136          // Fall row stride (us16): 6272 B, line-aligned rows
#define KP2  1056          // padded K for output GEMM (cols 0..1025 used, pad 30)
#define NCH  128           // scan chunks (R8 proven; 256 regressed in R9)
#define TC   (T_ / NCH)    // 16 timesteps per chunk

typedef unsigned short us16;
typedef __attribute__((ext_vector_type(8))) __bf16 bf16x8;
typedef __attribute__((ext_vector_type(4))) float  f32x4;

// Workspace layout (bytes). RCAT aliases PREP (WT+WoBf+Tcs, 10.49 MB >=
// 8.65 MB needed; all builders finish before scan_apply writes).
#define O_XBF    ((size_t)0)                 // x bf16: 8,388,608
#define O_PREP   ((size_t)8388608)
#define O_WT     (O_PREP)                    // WT bf16 3x1024x1024: 6,291,456
#define O_WOBF   (O_PREP + 6291456)          // Wo bf16: 2,097,152
#define O_TCS    (O_PREP + 8388608)          // Tcs bf16 1026x1024: 2,101,248
#define O_RCAT   (O_PREP)                    // Rcat bf16 4096x1056: 8,650,752
#define O_SFB    (O_PREP + 10489856)         // Sfb bf16 1056x1024: 2,162,688
#define O_MALLB  (O_SFB + 2162688)           // Mall bf16 3x1026x1024: 6,303,744
#define O_MOUTB  (O_MALLB + 6303744)         // MoutT bf16 1024x1056: 2,162,688
#define O_FALL   (O_MOUTB + 2162688)         // Fall bf16 4096x3136: 25,690,112
#define O_SSCAN  (O_FALL + 25690112)         // scan sums fp32: 10,506,240

__device__ __forceinline__ us16 f2b(float f) {
    union { float f; unsigned u; } v; v.f = f;
    unsigned r = v.u + 0x7FFFu + ((v.u >> 16) & 1u);
    return (us16)(r >> 16);
}

// packed bf16 pair -> float2 (bit-exact)
__device__ __forceinline__ float2 b2f2(unsigned w) {
    union { unsigned u; float f; } a, b;
    a.u = (w & 0xffffu) << 16;
    b.u = w & 0xffff0000u;
    return make_float2(a.f, b.f);
}

// async global->LDS DMA, 16 B per lane. LDS dest is wave-uniform base +
// lane*16 (HW-fixed); global src is per-lane.
__device__ __forceinline__ void gl_lds16(const us16* g, us16* l) {
    __builtin_amdgcn_global_load_lds(
        (const __attribute__((address_space(1))) unsigned*)g,
        (__attribute__((address_space(3))) unsigned*)l, 16, 0, 0);
}

// ---------------------------------------------------------------------------
// Fused prep (R11): x->bf16 | Wo->bf16 | W transpose x3 | Tcs+Sfb fused |
// Sfb pad rows. One dispatch, block-id ranges (block-uniform branch).
//   [0,4096)        cvt x
//   [4096,5120)     cvt Wo
//   [5120,8192)     transpose x3
//   [8192,12296)    Tcs AND Sfb rows 0..1025 (Sfb = s_f * same trig value)
//   [12296,12416)   Sfb pad rows 1026..1055 = 0
// Trig via __sinf/__cosf (v_sin/v_cos); error ~1e-7 << bf16 rounding.
// ---------------------------------------------------------------------------
__global__ __launch_bounds__(256)
void hrr_prep(const float* __restrict__ x,  const float* __restrict__ Wq,
              const float* __restrict__ Wk, const float* __restrict__ Wv,
              const float* __restrict__ Wo,
              us16* __restrict__ Xbf, us16* __restrict__ WT,
              us16* __restrict__ WoBf, us16* __restrict__ Tcs,
              us16* __restrict__ Sfb) {
    __shared__ float t[32][33];
    const int bid = blockIdx.x, tid = threadIdx.x;
    if (bid < 4096) {
        int i = bid * 256 + tid;
        float4 v = ((const float4*)x)[i];
        ushort4 o;
        o.x = f2b(v.x); o.y = f2b(v.y); o.z = f2b(v.z); o.w = f2b(v.w);
        ((ushort4*)Xbf)[i] = o;
    } else if (bid < 5120) {
        int i = (bid - 4096) * 256 + tid;
        float4 v = ((const float4*)Wo)[i];
        ushort4 o;
        o.x = f2b(v.x); o.y = f2b(v.y); o.z = f2b(v.z); o.w = f2b(v.w);
        ((ushort4*)WoBf)[i] = o;
    } else if (bid < 8192) {
        const int l  = bid - 5120;
        const int bz = l >> 10, l2 = l & 1023;
        const int bx = (l2 & 31) * 32, by = (l2 >> 5) * 32;
        const float* W = (bz == 0) ? Wq : (bz == 1) ? Wk : Wv;
        us16* O = WT + (size_t)bz * D_ * D_;
        const int tx = tid & 31, ty = tid >> 5;   // 32 x 8
#pragma unroll
        for (int i = 0; i < 32; i += 8)
            t[ty + i][tx] = W[(size_t)(by + ty + i) * D_ + bx + tx];
        __syncthreads();
#pragma unroll
        for (int i = 0; i < 32; i += 8)
            O[(size_t)(bx + ty + i) * D_ + by + tx] = f2b(t[tx][ty + i]);
    } else if (bid < 12296) {
        // rows interleaved: row 2f = cos(2*pi*f*e/1024), 2f+1 = -sin.
        // Sfb row r (r<1026) = s_f * Tcs row r.
        int idx = (bid - 8192) * 256 + tid;
        int r = idx >> 10, e = idx & 1023;
        int f = r >> 1;
        float ang = (float)((f * e) & 1023) * 6.135923151542565e-3f;
        float val = (r & 1) ? -__sinf(ang) : __cosf(ang);
        float s = (f == 0 || f == 512) ? (1.0f / 1024.0f) : (2.0f / 1024.0f);
        Tcs[idx] = f2b(val);
        Sfb[idx] = f2b(s * val);
    } else {
        // Sfb pad rows 1026..1055 = 0 (30*1024 = 30720 elems, 120 blocks)
        int idx2 = (bid - 12296) * 256 + tid;
        Sfb[1026 * 1024 + idx2] = 0;
    }
}

// ---------------------------------------------------------------------------
// bf16 MFMA GEMM core (128x64 tile, R7-verified): C(MxN) = A(MxK) @ B(NxK)^T.
// 256 threads = 4 waves of 32(M)x64(N), K-step 32. R3 sync structure: 2-buf,
// ONE barrier per K-step, gload_lds staging + granule XOR-swizzle (0 bank
// conflicts). 24 KB LDS -> 4 blocks/CU. Swapped mfma operands + LDS repack
// -> full-line contiguous row stores. Used for builders + output GEMM
// (the TLP-starved small GEMMs; main GEMM has its own 256^2 kernel).
// ---------------------------------------------------------------------------
template <bool OUT_BF16>
__device__ __forceinline__ void gemm_core64(
    const us16* __restrict__ A, const us16* __restrict__ B, void* __restrict__ Cv,
    int M, int N, int K, int lda, int ldb, int ldc, int Ncap,
    int bm, int bn, us16* smem) {
    us16* As = smem;                    // 2 x 4096 us16 (128x32 per buf)
    us16* Bs = smem + 8192;             // 2 x 2048 us16 (64x32 per buf)

    const int tid  = threadIdx.x;
    const int lane = tid & 63;
    const int wave = tid >> 6;
    const int wm = wave * 32;           // wave's M-offset (4 waves x 32 rows)

    const int r0    = tid >> 2;                      // 0..63 staging row
    const int g_lds = tid & 3;                       // LDS granule this thread fills
    const int g_src = g_lds ^ ((r0 >> 1) & 3);       // pre-swizzled source granule
    const int c4    = g_src * 8;                     // element offset in row

    int rA0 = bm + r0;      if (rA0 >= M) rA0 = M - 1;
    int rA1 = bm + 64 + r0; if (rA1 >= M) rA1 = M - 1;
    int rB0 = bn + r0;      if (rB0 >= N) rB0 = N - 1;
    const us16* pA0 = A + (size_t)rA0 * lda + c4;
    const us16* pA1 = A + (size_t)rA1 * lda + c4;
    const us16* pB0 = B + (size_t)rB0 * ldb + c4;

    f32x4 acc[2][4];
#pragma unroll
    for (int i = 0; i < 2; i++)
#pragma unroll
        for (int j = 0; j < 4; j++) acc[i][j] = (f32x4){0.f, 0.f, 0.f, 0.f};

    const int fr = lane & 15;
    const int gq = ((lane >> 4) ^ ((fr >> 1) & 3)) * 8;

    const int wb = wave * 512;          // wave-uniform LDS base (us16 units)
#define STAGE_TILE(buf, ko)                                  \
    do {                                                     \
        us16* a_ = As + (buf) * 4096 + wb;                   \
        us16* b_ = Bs + (buf) * 2048 + wb;                   \
        gl_lds16(pA0 + (ko), a_);                            \
        gl_lds16(pA1 + (ko), a_ + 2048);                     \
        gl_lds16(pB0 + (ko), b_);                            \
    } while (0)

    STAGE_TILE(0, 0);
    __syncthreads();

    int cur = 0;
    for (int k0 = 0; k0 < K; k0 += 32) {
        const int kn = k0 + 32;
        if (kn < K) STAGE_TILE(cur ^ 1, kn);

        const us16* Ac = As + cur * 4096;
        const us16* Bc = Bs + cur * 2048;
        bf16x8 af[2], bfr[4];
#pragma unroll
        for (int i = 0; i < 2; i++)
            af[i] = *(const bf16x8*)(Ac + (wm + i * 16 + fr) * 32 + gq);
#pragma unroll
        for (int j = 0; j < 4; j++)
            bfr[j] = *(const bf16x8*)(Bc + (j * 16 + fr) * 32 + gq);
        // SWAPPED operands: lane holds 4 consecutive C-cols:
        // C row = bm+wm+i*16+(lane&15), C col = bn+j*16+(lane>>4)*4+reg
#pragma unroll
        for (int i = 0; i < 2; i++)
#pragma unroll
            for (int j = 0; j < 4; j++)
                acc[i][j] = __builtin_amdgcn_mfma_f32_16x16x32_bf16(bfr[j], af[i], acc[i][j], 0, 0, 0);

        __syncthreads();
        cur ^= 1;
    }
#undef STAGE_TILE

    // ---- epilogue: LDS repack -> full-line contiguous row stores ----
    const int cl  = lane & 15;
    const int rq  = (lane >> 4) * 4;
    float* lbuf = (float*)smem;
#pragma unroll
    for (int p = 0; p < 4; ++p) {
        __syncthreads();
        if (wave == p) {
#pragma unroll
            for (int i = 0; i < 2; ++i) {
                const int rl = i * 16 + cl;
#pragma unroll
                for (int j = 0; j < 4; ++j)
                    *(f32x4*)(lbuf + rl * 68 + j * 16 + rq) = acc[i][j];
            }
        }
        __syncthreads();
        const int rbase = bm + p * 32;
        if (OUT_BF16) {
            us16* C = (us16*)Cv;
            const int row = tid >> 3, col = (tid * 8) & 63;   // 32x64, 8/thread
            const int grow = rbase + row, gcol = bn + col;
            if (grow < M && gcol + 8 <= Ncap) {
                const float* s = lbuf + row * 68 + col;
                uint4 o;
                o.x = (unsigned)f2b(s[0]) | ((unsigned)f2b(s[1]) << 16);
                o.y = (unsigned)f2b(s[2]) | ((unsigned)f2b(s[3]) << 16);
                o.z = (unsigned)f2b(s[4]) | ((unsigned)f2b(s[5]) << 16);
                o.w = (unsigned)f2b(s[6]) | ((unsigned)f2b(s[7]) << 16);
                *(uint4*)(C + (size_t)grow * ldc + gcol) = o;
            }
        } else {
            float* C = (float*)Cv;
#pragma unroll
            for (int rr = 0; rr < 2; ++rr) {
                const int idx = rr * 1024 + tid * 4;          // 32x64, 2xfloat4
                const int row = idx >> 6, col = idx & 63;
                const int grow = rbase + row, gcol = bn + col;
                if (grow < M && gcol + 4 <= Ncap)
                    *(float4*)(C + (size_t)grow * ldc + gcol) =
                        *(const float4*)(lbuf + row * 68 + col);
            }
        }
    }
}

// Generic GEMM (128x64 tiles) with bijective XCD-chunk swizzle (nwg%8==0).
template <bool OUT_BF16>
__global__ __launch_bounds__(256, 4)
void hrr_gemm(const us16* __restrict__ A, const us16* __restrict__ B,
              void* __restrict__ C, int M, int N, int K,
              int lda, int ldb, int ldc, int Ncap, int swz) {
    __shared__ us16 smem[12288];        // 24 KB
    int bx = blockIdx.x, by = blockIdx.y;
    if (swz) {
        const int gx = gridDim.x;
        const int id = bx + gx * by;
        const int q = (gx * gridDim.y) >> 3;
        const int nid = (id & 7) * q + (id >> 3);
        bx = nid % gx; by = nid / gx;
    }
    gemm_core64<OUT_BF16>(A, B, C, M, N, K, lda, ldb, ldc, Ncap,
                          by * 128, bx * 64, smem);
}

// Fused builders (128x64 tiles, R7-verified): z<3 -> Mall_z = Tcs @ WT_z^T;
// z==3 -> MoutT = WoBf @ Sfb^T. Grid (17,9,4); out-of-range tiles exit.
__global__ __launch_bounds__(256, 4)
void hrr_gemm_builders(const us16* __restrict__ Tcs, const us16* __restrict__ WT,
                       us16* __restrict__ MallB, const us16* __restrict__ WoBf,
                       const us16* __restrict__ Sfb, us16* __restrict__ MoutB) {
    __shared__ us16 smem[12288];
    const int z = blockIdx.z;
    if (z < 3) {
        if (blockIdx.x >= 16) return;              // 16 n-tiles of 64 (N=1024)
        gemm_core64<true>(Tcs, WT + (size_t)z * D_ * D_,
                          MallB + (size_t)z * 1026 * 1024,
                          1026, 1024, 1024, 1024, 1024, 1024, 1024,
                          blockIdx.y * 128, blockIdx.x * 64, smem);
    } else {
        if (blockIdx.y >= 8) return;               // 8 m-tiles of 128 (M=1024)
        gemm_core64<true>(WoBf, Sfb, MoutB,
                          1024, KP2, 1024, 1024, 1024, KP2, KP2,
                          blockIdx.y * 128, blockIdx.x * 64, smem);
    }
}

// ---------------------------------------------------------------------------
// Main GEMM: Fall(4096 x 3078 cols used, bf16, ldc=LFP) = Xbf @ MallB^T.
// 256x256 tile, BK=64, 512 threads = 8 waves (2M x 4N). Phase-pipelined
// (T3+T4): per K-tile issue next tile's 8 global_load_lds first, then 4
// quadrant phases {snake ds_read -> setprio MFMA} split by raw s_barrier
// (loads in flight across barriers); single vmcnt(0) at tile end.
// ---------------------------------------------------------------------------
__global__ __launch_bounds__(512, 2)
void hrr_gemm_main(const us16* __restrict__ A, const us16* __restrict__ B,
                   us16* __restrict__ C) {
    __shared__ us16 smem[65536];          // 128 KB
    us16* Asb = smem;                     // [2][256*64]
    us16* Bsb = smem + 32768;

    const int tid  = threadIdx.x;
    const int lane = tid & 63;
    const int wave = tid >> 6;

    // bijective XCD-chunk swizzle over 13x16 = 208 blocks (208 % 8 == 0)
    int id = blockIdx.x + 13 * blockIdx.y;
    id = (id & 7) * 26 + (id >> 3);
    const int bx = id % 13, by = id / 13;
    const int bm = by * 256, bn = bx * 256;

    // staging source pointers: 4 row-groups for A and B (8 gl_lds per tile)
    const int srow = tid >> 3;                    // 0..63
    const int sgr  = (tid & 7) ^ (srow & 7);      // swizzled source granule
    const us16* gA[4];
    const us16* gB[4];
#pragma unroll
    for (int g = 0; g < 4; ++g) {
        int ra = bm + g * 64 + srow; if (ra > NTOK - 1) ra = NTOK - 1;
        int rb = bn + g * 64 + srow; if (rb > LF - 1)   rb = LF - 1;
        gA[g] = A + (size_t)ra * 1024 + sgr * 8;
        gB[g] = B + (size_t)rb * 1024 + sgr * 8;
    }

    f32x4 acc[8][4];
#pragma unroll
    for (int i = 0; i < 8; i++)
#pragma unroll
        for (int j = 0; j < 4; j++) acc[i][j] = (f32x4){0.f, 0.f, 0.f, 0.f};

    const int wmw = (wave >> 2) * 128;    // wave M-offset (2 halves)
    const int wnw = (wave & 3) * 64;      // wave N-offset (4 quarters)
    const int fr  = lane & 15;
    const int gr  = lane >> 4;            // 0..3
    const int l7  = lane & 7;

#define STAGE3(buf, ko)                                            \
    do {                                                           \
        us16* a_ = Asb + (buf) * 16384 + wave * 512;               \
        us16* b_ = Bsb + (buf) * 16384 + wave * 512;               \
        gl_lds16(gA[0] + (ko), a_);                                \
        gl_lds16(gA[1] + (ko), a_ + 4096);                         \
        gl_lds16(gA[2] + (ko), a_ + 8192);                         \
        gl_lds16(gA[3] + (ko), a_ + 12288);                        \
        gl_lds16(gB[0] + (ko), b_);                                \
        gl_lds16(gB[1] + (ko), b_ + 4096);                         \
        gl_lds16(gB[2] + (ko), b_ + 8192);                         \
        gl_lds16(gB[3] + (ko), b_ + 12288);                        \
    } while (0)

#define RBAR                                                       \
    do {                                                           \
        asm volatile("" ::: "memory");                             \
        __builtin_amdgcn_s_barrier();                              \
        asm volatile("" ::: "memory");                             \
    } while (0)

#define LOAD_A(ih)                                                              \
    do {                                                                        \
        _Pragma("unroll")                                                       \
        for (int i = 0; i < 4; ++i)                                             \
            _Pragma("unroll")                                                   \
            for (int ks = 0; ks < 2; ++ks)                                      \
                af[i][ks] = *(const bf16x8*)(Ac +                               \
                    (wmw + (ih) * 64 + i * 16 + fr) * 64 +                      \
                    (((ks << 2) | gr) ^ l7) * 8);                               \
    } while (0)

#define LOAD_B(jh)                                                              \
    do {                                                                        \
        _Pragma("unroll")                                                       \
        for (int j = 0; j < 2; ++j)                                             \
            _Pragma("unroll")                                                   \
            for (int ks = 0; ks < 2; ++ks)                                      \
                bfr[j][ks] = *(const bf16x8*)(Bc +                              \
                    (wnw + (jh) * 32 + j * 16 + fr) * 64 +                      \
                    (((ks << 2) | gr) ^ l7) * 8);                               \
    } while (0)

#define MFMA_Q(ih, jh)                                                          \
    do {                                                                        \
        __builtin_amdgcn_s_setprio(1);                                          \
        _Pragma("unroll")                                                       \
        for (int i = 0; i < 4; ++i)                                             \
            _Pragma("unroll")                                                   \
            for (int j = 0; j < 2; ++j)                                         \
                _Pragma("unroll")                                               \
                for (int ks = 0; ks < 2; ++ks)                                  \
                    acc[(ih) * 4 + i][(jh) * 2 + j] =                           \
                        __builtin_amdgcn_mfma_f32_16x16x32_bf16(                \
                            bfr[j][ks], af[i][ks],                              \
                            acc[(ih) * 4 + i][(jh) * 2 + j], 0, 0, 0);          \
        __builtin_amdgcn_s_setprio(0);                                          \
    } while (0)

    // prologue: stage tile 0, full drain
    STAGE3(0, 0);
    asm volatile("s_waitcnt vmcnt(0)" ::: "memory");
    __builtin_amdgcn_s_barrier();
    asm volatile("" ::: "memory");

    int cur = 0;
#pragma unroll 1
    for (int t = 0; t < 16; ++t) {
        if (t < 15) STAGE3(cur ^ 1, (t + 1) * 64);   // async, stays in flight

        const us16* Ac = Asb + cur * 16384;
        const us16* Bc = Bsb + cur * 16384;
        bf16x8 af[4][2], bfr[2][2];

        // snake order: (0,0) -> (0,1) -> (1,1) -> (1,0); reuse af/bf sets
        LOAD_A(0); LOAD_B(0); MFMA_Q(0, 0); RBAR;
        LOAD_B(1);            MFMA_Q(0, 1); RBAR;
        LOAD_A(1);            MFMA_Q(1, 1); RBAR;
        LOAD_B(0);            MFMA_Q(1, 0);
        asm volatile("s_waitcnt vmcnt(0)" ::: "memory");  // next tile staged
        __builtin_amdgcn_s_barrier();
        asm volatile("" ::: "memory");
        cur ^= 1;
    }
#undef STAGE3
#undef LOAD_A
#undef LOAD_B
#undef MFMA_Q
#undef RBAR

    // ---- epilogue: per-wave LDS repack -> full-line bf16 row stores ----
    __syncthreads();
    float* lw = (float*)smem + wave * (32 * 68);     // 8.7 KB per wave
    const int cl = lane & 15;
    const int rq = (lane >> 4) * 4;
#pragma unroll
    for (int p = 0; p < 4; ++p) {
#pragma unroll
        for (int ii = 0; ii < 2; ++ii) {
            const int ifr = p * 2 + ii;
#pragma unroll
            for (int j = 0; j < 4; ++j)
                *(f32x4*)(lw + (ii * 16 + cl) * 68 + j * 16 + rq) = acc[ifr][j];
        }
        __syncthreads();
#pragma unroll
        for (int rr = 0; rr < 4; ++rr) {
            const int idx = rr * 512 + lane * 8;     // 32 rows x 64 cols
            const int row = idx >> 6, col = idx & 63;
            const int grow = bm + wmw + p * 32 + row;
            const int gcol = bn + wnw + col;
            if (gcol + 8 <= LFP) {
                const float* s = lw + row * 68 + col;
                uint4 o;
                o.x = (unsigned)f2b(s[0]) | ((unsigned)f2b(s[1]) << 16);
                o.y = (unsigned)f2b(s[2]) | ((unsigned)f2b(s[3]) << 16);
                o.z = (unsigned)f2b(s[4]) | ((unsigned)f2b(s[5]) << 16);
                o.w = (unsigned)f2b(s[6]) | ((unsigned)f2b(s[7]) << 16);
                *(uint4*)(C + (size_t)grow * LFP + gcol) = o;
            }
        }
        __syncthreads();
    }
}

// ---------------------------------------------------------------------------
// Scan phase 1: chunk sums. Grid (NCH, B_, 2) f-halves, 256 threads.
// T14 issue-early prefetch — next row's k/v loaded into regs right after the
// LDS-write barrier; compute phase + barrier hides the load latency.
// Fall u32 layout per row (R32=1568): q@0, k@513, v@1026.
// ---------------------------------------------------------------------------
__global__ __launch_bounds__(256, 4)
void hrr_scan_sums(const us16* __restrict__ Fall, const int* __restrict__ perms,
                   float* __restrict__ S) {
    const int n = blockIdx.x, b = blockIdx.y, half = blockIdx.z;
    const int tid = threadIdx.x;
    const int f0 = half * 256;
    __shared__ float2 kc[F_], vc[257];

    float aR[2][C_], aI[2][C_];
    int gg[2][C_];
#pragma unroll
    for (int i = 0; i < 2; i++) {
        const int f = (i == 0) ? (f0 + tid) : 512;
        const bool act = (i == 0) || (half == 1 && tid == 0);
#pragma unroll
        for (int c = 0; c < C_; c++) {
            gg[i][c] = act ? perms[c * F_ + f] : 0;
            aR[i][c] = aI[i][c] = 0.f;
        }
    }

    const unsigned* rowb =
        (const unsigned*)(Fall + (size_t)(b * T_ + n * TC) * LFP);
    const int R32 = LFP / 2;            // 1568 u32 per row

    unsigned rk0, rk1, rk2 = 0, rv0, rv1 = 0;
#define SFETCH(tl)                                                   \
    do {                                                             \
        const unsigned* r_ = rowb + (size_t)(tl) * R32;              \
        rk0 = r_[513 + tid];                                         \
        rk1 = r_[769 + tid];                                         \
        rv0 = r_[1026 + f0 + tid];                                   \
        if (tid == 0) { rk2 = r_[1025]; rv1 = r_[1538]; }            \
    } while (0)

    SFETCH(0);
    for (int tl = 0; tl < TC; tl++) {
        __syncthreads();                 // prev iter's LDS consumers done
        kc[tid]       = b2f2(rk0);
        kc[256 + tid] = b2f2(rk1);
        vc[tid]       = b2f2(rv0);
        if (tid == 0) { kc[512] = b2f2(rk2); if (half) vc[256] = b2f2(rv1); }
        __syncthreads();
        if (tl + 1 < TC) SFETCH(tl + 1); // issue next row early (async)
#pragma unroll
        for (int i = 0; i < 2; i++) {
            const int lv = (i == 0) ? tid : 256;
            if (i == 0 || (half == 1 && tid == 0)) {
                float2 v = vc[lv];
#pragma unroll
                for (int c = 0; c < C_; c++) {
                    float2 k = kc[gg[i][c]];
                    aR[i][c] += k.x * v.x - k.y * v.y;
                    aI[i][c] += k.x * v.y + k.y * v.x;
                }
            }
        }
    }
#undef SFETCH
#pragma unroll
    for (int i = 0; i < 2; i++) {
        const int f = (i == 0) ? (f0 + tid) : 512;
        if (i == 0 || (half == 1 && tid == 0)) {
#pragma unroll
            for (int c = 0; c < C_; c++) {
                size_t a = ((((size_t)c * B_ + b) * NCH + n) * F_ + f) * 2;
                S[a] = aR[i][c]; S[a + 1] = aI[i][c];
            }
        }
    }
}

// ---------------------------------------------------------------------------
// Scan phase 2: exclusive prefix over chunks, per (c,b,f). 8-way unrolled.
// ---------------------------------------------------------------------------
__global__ void hrr_scan_prefix(float* __restrict__ S) {
    int tid = blockIdx.x * 256 + threadIdx.x;
    if (tid >= C_ * B_ * F_) return;
    int c = tid / (B_ * F_);
    int r = tid % (B_ * F_);
    int b = r / F_, f = r % F_;
    size_t base = (((size_t)c * B_ + b) * NCH) * F_ + f;
    float runR = 0.f, runI = 0.f;
    for (int n0 = 0; n0 < NCH; n0 += 8) {
        float tR[8], tI[8];
#pragma unroll
        for (int u = 0; u < 8; u++) {
            size_t a = (base + (size_t)(n0 + u) * F_) * 2;
            tR[u] = S[a]; tI[u] = S[a + 1];
        }
#pragma unroll
        for (int u = 0; u < 8; u++) {
            size_t a = (base + (size_t)(n0 + u) * F_) * 2;
            S[a] = runR; S[a + 1] = runI;
            runR += tR[u]; runI += tI[u];
        }
    }
}

// ---------------------------------------------------------------------------
// Scan phase 3: running kv in regs, r = mean_c kv*conj(fqp) -> Rcat.
// T14 issue-early prefetch of next row's q/k/v (same pattern as sums).
// ---------------------------------------------------------------------------
__global__ __launch_bounds__(256, 4)
void hrr_scan_apply(const us16* __restrict__ Fall, const int* __restrict__ perms,
                    const float* __restrict__ S, us16* __restrict__ Rcat) {
    const int n = blockIdx.x, b = blockIdx.y, half = blockIdx.z;
    const int tid = threadIdx.x;
    const int f0 = half * 256;
    __shared__ float2 qc[F_], kc[F_], vc[257];

    float kvR[2][C_], kvI[2][C_];
    int gg[2][C_];
#pragma unroll
    for (int i = 0; i < 2; i++) {
        const int f = (i == 0) ? (f0 + tid) : 512;
        const bool act = (i == 0) || (half == 1 && tid == 0);
#pragma unroll
        for (int c = 0; c < C_; c++) {
            gg[i][c] = act ? perms[c * F_ + f] : 0;
            if (act) {
                size_t a = ((((size_t)c * B_ + b) * NCH + n) * F_ + f) * 2;
                kvR[i][c] = S[a]; kvI[i][c] = S[a + 1];
            } else { kvR[i][c] = 0.f; kvI[i][c] = 0.f; }
        }
    }

    const unsigned* rowb =
        (const unsigned*)(Fall + (size_t)(b * T_ + n * TC) * LFP);
    const int R32 = LFP / 2;            // 1568 u32 per row

    unsigned rq0, rq1, rq2 = 0, rk0, rk1, rk2 = 0, rv0, rv1 = 0;
#define AFETCH(tl)                                                   \
    do {                                                             \
        const unsigned* r_ = rowb + (size_t)(tl) * R32;              \
        rq0 = r_[tid];       rq1 = r_[256 + tid];                    \
        rk0 = r_[513 + tid]; rk1 = r_[769 + tid];                    \
        rv0 = r_[1026 + f0 + tid];                                   \
        if (tid == 0) { rq2 = r_[512]; rk2 = r_[1025]; rv1 = r_[1538]; } \
    } while (0)

    AFETCH(0);
    for (int tl = 0; tl < TC; tl++) {
        const int tt = b * T_ + n * TC + tl;
        __syncthreads();                 // prev iter's LDS consumers done
        qc[tid]       = b2f2(rq0);
        qc[256 + tid] = b2f2(rq1);
        kc[tid]       = b2f2(rk0);
        kc[256 + tid] = b2f2(rk1);
        vc[tid]       = b2f2(rv0);
        if (tid == 0) {
            qc[512] = b2f2(rq2); kc[512] = b2f2(rk2);
            if (half) vc[256] = b2f2(rv1);
        }
        __syncthreads();
        if (tl + 1 < TC) AFETCH(tl + 1); // issue next row early (async)
        unsigned* out32 = (unsigned*)(Rcat + (size_t)tt * KP2);
#pragma unroll
        for (int i = 0; i < 2; i++) {
            const int f = (i == 0) ? (f0 + tid) : 512;
            const int lv = (i == 0) ? tid : 256;
            if (i == 0 || (half == 1 && tid == 0)) {
                float2 v = vc[lv];
                float accR = 0.f, accI = 0.f;
#pragma unroll
                for (int c = 0; c < C_; c++) {
                    int g = gg[i][c];
                    float2 k = kc[g];
                    float nR = kvR[i][c] + k.x * v.x - k.y * v.y;
                    float nI = kvI[i][c] + k.x * v.y + k.y * v.x;
                    kvR[i][c] = nR; kvI[i][c] = nI;
                    float2 q = qc[g];
                    accR += nR * q.x + nI * q.y;
                    accI += nI * q.x - nR * q.y;
                }
                out32[f] = (unsigned)f2b(accR * 0.1f)
                         | ((unsigned)f2b(accI * 0.1f) << 16);
            }
        }
        if (half == 0 && tid < 15)                  // zero pad cols 1026..1055
            out32[513 + tid] = 0;
    }
#undef AFETCH
}

// ---------------------------------------------------------------------------
extern "C" void kernel_launch(void* const* d_in, const int* in_sizes, int n_in,
                              void* d_out, int out_size, void* d_ws, size_t ws_size,
                              hipStream_t stream) {
    const float* x  = (const float*)d_in[0];
    const float* Wq = (const float*)d_in[1];
    const float* Wk = (const float*)d_in[2];
    const float* Wv = (const float*)d_in[3];
    const float* Wo = (const float*)d_in[4];
    const int* perms = (const int*)d_in[5];
    float* out = (float*)d_out;

    char* ws = (char*)d_ws;
    us16* Xbf   = (us16*)(ws + O_XBF);
    us16* WT    = (us16*)(ws + O_WT);
    us16* WoBf  = (us16*)(ws + O_WOBF);
    us16* Tcs   = (us16*)(ws + O_TCS);
    us16* Sfb   = (us16*)(ws + O_SFB);
    us16* MallB = (us16*)(ws + O_MALLB);
    us16* MoutB = (us16*)(ws + O_MOUTB);
    us16* Rcat  = (us16*)(ws + O_RCAT);
    us16* Fall  = (us16*)(ws + O_FALL);
    float* Ssc  = (float*)(ws + O_SSCAN);

    // fused prep: cvt x / cvt Wo / transpose x3 / Tcs+Sfb fused / Sfb pad
    hrr_prep<<<12416, 256, 0, stream>>>(x, Wq, Wk, Wv, Wo, Xbf, WT, WoBf, Tcs, Sfb);

    // fused builders: Mall x3 + MoutT, one dispatch, 128x64 tiles
    hrr_gemm_builders<<<dim3(17, 9, 4), 256, 0, stream>>>(Tcs, WT, MallB, WoBf, Sfb, MoutB);

    // main GEMM: 256x256 phase-pipelined kernel, grid 13x16 = 208 blocks
    hrr_gemm_main<<<dim3(13, 16), 512, 0, stream>>>(Xbf, MallB, Fall);

    // chunked causal scan (NCH=128, TC=16; scan kernels T14-prefetched)
    hrr_scan_sums<<<dim3(NCH, B_, 2), 256, 0, stream>>>(Fall, perms, Ssc);
    hrr_scan_prefix<<<(C_ * B_ * F_ + 255) / 256, 256, 0, stream>>>(Ssc);
    hrr_scan_apply<<<dim3(NCH, B_, 2), 256, 0, stream>>>(Fall, perms, Ssc, Rcat);

    // output GEMM: out(4096x1024 fp32) = Rcat(4096x1056) @ MoutB^T
    // 128x64 tiles -> 16x32 = 512 blocks (2/CU), XCD swizzle
    hrr_gemm<false><<<dim3(16, 32), 256, 0, stream>>>(
        Rcat, MoutB, out, NTOK, D_, KP2, KP2, KP2, D_, D_, 1);
}

// Round 12
// 213.555 us; speedup vs baseline: 1.1630x; 1.0046x over previous
//
#include <hip/hip_runtime.h>
#include <math.h>

// Problem constants
#define B_   2
#define T_   2048
#define D_   1024
#define C_   10
#define F_   513
#define NTOK (B_ * T_)     // 4096 rows
#define LF   3078          // Fall logical cols: [q(1026) | k(1026) | v(1026)] interleaved re/im
#define LFP  3136          // Fall row stride (us16): 6272 B, line-aligned rows
#define KP2  1056          // padded K for output GEMM (cols 0..1025 used, pad 30)
#define NCH  128           // scan chunks (R8 proven; 256 regressed in R9)
#define TC   (T_ / NCH)    // 16 timesteps per chunk

typedef unsigned short us16;
typedef __attribute__((ext_vector_type(8))) __bf16 bf16x8;
typedef __attribute__((ext_vector_type(4))) float  f32x4;

// Workspace layout (bytes). RCAT aliases PREP (WT+WoBf+Tcs, 10.49 MB >=
// 8.65 MB needed; all builders finish before scan_apply writes).
#define O_XBF    ((size_t)0)                 // x bf16: 8,388,608
#define O_PREP   ((size_t)8388608)
#define O_WT     (O_PREP)                    // WT bf16 3x1024x1024: 6,291,456
#define O_WOBF   (O_PREP + 6291456)          // Wo bf16: 2,097,152
#define O_TCS    (O_PREP + 8388608)          // Tcs bf16 1026x1024: 2,101,248
#define O_RCAT   (O_PREP)                    // Rcat bf16 4096x1056: 8,650,752
#define O_SFB    (O_PREP + 10489856)         // Sfb bf16 1056x1024: 2,162,688
#define O_MALLB  (O_SFB + 2162688)           // Mall bf16 3x1026x1024: 6,303,744
#define O_MOUTB  (O_MALLB + 6303744)         // MoutT bf16 1024x1056: 2,162,688
#define O_FALL   (O_MOUTB + 2162688)         // Fall bf16 4096x3136: 25,690,112
#define O_SSCAN  (O_FALL + 25690112)         // scan sums fp32: 10,506,240

__device__ __forceinline__ us16 f2b(float f) {
    union { float f; unsigned u; } v; v.f = f;
    unsigned r = v.u + 0x7FFFu + ((v.u >> 16) & 1u);
    return (us16)(r >> 16);
}

// packed bf16 pair -> float2 (bit-exact)
__device__ __forceinline__ float2 b2f2(unsigned w) {
    union { unsigned u; float f; } a, b;
    a.u = (w & 0xffffu) << 16;
    b.u = w & 0xffff0000u;
    return make_float2(a.f, b.f);
}

// async global->LDS DMA, 16 B per lane. LDS dest is wave-uniform base +
// lane*16 (HW-fixed); global src is per-lane.
__device__ __forceinline__ void gl_lds16(const us16* g, us16* l) {
    __builtin_amdgcn_global_load_lds(
        (const __attribute__((address_space(1))) unsigned*)g,
        (__attribute__((address_space(3))) unsigned*)l, 16, 0, 0);
}

// ---------------------------------------------------------------------------
// Fused prep: x->bf16 | Wo->bf16 | W transpose x3 | Tcs+Sfb fused | Sfb pad.
// One dispatch, block-id ranges (block-uniform branch).
// Trig via __sinf/__cosf (v_sin/v_cos); error ~1e-7 << bf16 rounding.
// ---------------------------------------------------------------------------
__global__ __launch_bounds__(256)
void hrr_prep(const float* __restrict__ x,  const float* __restrict__ Wq,
              const float* __restrict__ Wk, const float* __restrict__ Wv,
              const float* __restrict__ Wo,
              us16* __restrict__ Xbf, us16* __restrict__ WT,
              us16* __restrict__ WoBf, us16* __restrict__ Tcs,
              us16* __restrict__ Sfb) {
    __shared__ float t[32][33];
    const int bid = blockIdx.x, tid = threadIdx.x;
    if (bid < 4096) {
        int i = bid * 256 + tid;
        float4 v = ((const float4*)x)[i];
        ushort4 o;
        o.x = f2b(v.x); o.y = f2b(v.y); o.z = f2b(v.z); o.w = f2b(v.w);
        ((ushort4*)Xbf)[i] = o;
    } else if (bid < 5120) {
        int i = (bid - 4096) * 256 + tid;
        float4 v = ((const float4*)Wo)[i];
        ushort4 o;
        o.x = f2b(v.x); o.y = f2b(v.y); o.z = f2b(v.z); o.w = f2b(v.w);
        ((ushort4*)WoBf)[i] = o;
    } else if (bid < 8192) {
        const int l  = bid - 5120;
        const int bz = l >> 10, l2 = l & 1023;
        const int bx = (l2 & 31) * 32, by = (l2 >> 5) * 32;
        const float* W = (bz == 0) ? Wq : (bz == 1) ? Wk : Wv;
        us16* O = WT + (size_t)bz * D_ * D_;
        const int tx = tid & 31, ty = tid >> 5;   // 32 x 8
#pragma unroll
        for (int i = 0; i < 32; i += 8)
            t[ty + i][tx] = W[(size_t)(by + ty + i) * D_ + bx + tx];
        __syncthreads();
#pragma unroll
        for (int i = 0; i < 32; i += 8)
            O[(size_t)(bx + ty + i) * D_ + by + tx] = f2b(t[tx][ty + i]);
    } else if (bid < 12296) {
        // rows interleaved: row 2f = cos(2*pi*f*e/1024), 2f+1 = -sin.
        // Sfb row r (r<1026) = s_f * Tcs row r.
        int idx = (bid - 8192) * 256 + tid;
        int r = idx >> 10, e = idx & 1023;
        int f = r >> 1;
        float ang = (float)((f * e) & 1023) * 6.135923151542565e-3f;
        float val = (r & 1) ? -__sinf(ang) : __cosf(ang);
        float s = (f == 0 || f == 512) ? (1.0f / 1024.0f) : (2.0f / 1024.0f);
        Tcs[idx] = f2b(val);
        Sfb[idx] = f2b(s * val);
    } else {
        // Sfb pad rows 1026..1055 = 0 (30*1024 = 30720 elems, 120 blocks)
        int idx2 = (bid - 12296) * 256 + tid;
        Sfb[1026 * 1024 + idx2] = 0;
    }
}

// ---------------------------------------------------------------------------
// bf16 MFMA GEMM core (128x64 tile, R7-verified): C(MxN) = A(MxK) @ B(NxK)^T.
// 256 threads = 4 waves of 32(M)x64(N), K-step 32. 2-buf, ONE barrier per
// K-step, gload_lds staging + granule XOR-swizzle (0 bank conflicts).
// 24 KB LDS -> 4 blocks/CU. Swapped mfma operands + LDS repack -> full-line
// contiguous row stores. Used for builders + output GEMM.
// ---------------------------------------------------------------------------
template <bool OUT_BF16>
__device__ __forceinline__ void gemm_core64(
    const us16* __restrict__ A, const us16* __restrict__ B, void* __restrict__ Cv,
    int M, int N, int K, int lda, int ldb, int ldc, int Ncap,
    int bm, int bn, us16* smem) {
    us16* As = smem;                    // 2 x 4096 us16 (128x32 per buf)
    us16* Bs = smem + 8192;             // 2 x 2048 us16 (64x32 per buf)

    const int tid  = threadIdx.x;
    const int lane = tid & 63;
    const int wave = tid >> 6;
    const int wm = wave * 32;           // wave's M-offset (4 waves x 32 rows)

    const int r0    = tid >> 2;                      // 0..63 staging row
    const int g_lds = tid & 3;                       // LDS granule this thread fills
    const int g_src = g_lds ^ ((r0 >> 1) & 3);       // pre-swizzled source granule
    const int c4    = g_src * 8;                     // element offset in row

    int rA0 = bm + r0;      if (rA0 >= M) rA0 = M - 1;
    int rA1 = bm + 64 + r0; if (rA1 >= M) rA1 = M - 1;
    int rB0 = bn + r0;      if (rB0 >= N) rB0 = N - 1;
    const us16* pA0 = A + (size_t)rA0 * lda + c4;
    const us16* pA1 = A + (size_t)rA1 * lda + c4;
    const us16* pB0 = B + (size_t)rB0 * ldb + c4;

    f32x4 acc[2][4];
#pragma unroll
    for (int i = 0; i < 2; i++)
#pragma unroll
        for (int j = 0; j < 4; j++) acc[i][j] = (f32x4){0.f, 0.f, 0.f, 0.f};

    const int fr = lane & 15;
    const int gq = ((lane >> 4) ^ ((fr >> 1) & 3)) * 8;

    const int wb = wave * 512;          // wave-uniform LDS base (us16 units)
#define STAGE_TILE(buf, ko)                                  \
    do {                                                     \
        us16* a_ = As + (buf) * 4096 + wb;                   \
        us16* b_ = Bs + (buf) * 2048 + wb;                   \
        gl_lds16(pA0 + (ko), a_);                            \
        gl_lds16(pA1 + (ko), a_ + 2048);                     \
        gl_lds16(pB0 + (ko), b_);                            \
    } while (0)

    STAGE_TILE(0, 0);
    __syncthreads();

    int cur = 0;
    for (int k0 = 0; k0 < K; k0 += 32) {
        const int kn = k0 + 32;
        if (kn < K) STAGE_TILE(cur ^ 1, kn);

        const us16* Ac = As + cur * 4096;
        const us16* Bc = Bs + cur * 2048;
        bf16x8 af[2], bfr[4];
#pragma unroll
        for (int i = 0; i < 2; i++)
            af[i] = *(const bf16x8*)(Ac + (wm + i * 16 + fr) * 32 + gq);
#pragma unroll
        for (int j = 0; j < 4; j++)
            bfr[j] = *(const bf16x8*)(Bc + (j * 16 + fr) * 32 + gq);
        // SWAPPED operands: lane holds 4 consecutive C-cols:
        // C row = bm+wm+i*16+(lane&15), C col = bn+j*16+(lane>>4)*4+reg
#pragma unroll
        for (int i = 0; i < 2; i++)
#pragma unroll
            for (int j = 0; j < 4; j++)
                acc[i][j] = __builtin_amdgcn_mfma_f32_16x16x32_bf16(bfr[j], af[i], acc[i][j], 0, 0, 0);

        __syncthreads();
        cur ^= 1;
    }
#undef STAGE_TILE

    // ---- epilogue: LDS repack -> full-line contiguous row stores ----
    const int cl  = lane & 15;
    const int rq  = (lane >> 4) * 4;
    float* lbuf = (float*)smem;
#pragma unroll
    for (int p = 0; p < 4; ++p) {
        __syncthreads();
        if (wave == p) {
#pragma unroll
            for (int i = 0; i < 2; ++i) {
                const int rl = i * 16 + cl;
#pragma unroll
                for (int j = 0; j < 4; ++j)
                    *(f32x4*)(lbuf + rl * 68 + j * 16 + rq) = acc[i][j];
            }
        }
        __syncthreads();
        const int rbase = bm + p * 32;
        if (OUT_BF16) {
            us16* C = (us16*)Cv;
            const int row = tid >> 3, col = (tid * 8) & 63;   // 32x64, 8/thread
            const int grow = rbase + row, gcol = bn + col;
            if (grow < M && gcol + 8 <= Ncap) {
                const float* s = lbuf + row * 68 + col;
                uint4 o;
                o.x = (unsigned)f2b(s[0]) | ((unsigned)f2b(s[1]) << 16);
                o.y = (unsigned)f2b(s[2]) | ((unsigned)f2b(s[3]) << 16);
                o.z = (unsigned)f2b(s[4]) | ((unsigned)f2b(s[5]) << 16);
                o.w = (unsigned)f2b(s[6]) | ((unsigned)f2b(s[7]) << 16);
                *(uint4*)(C + (size_t)grow * ldc + gcol) = o;
            }
        } else {
            float* C = (float*)Cv;
#pragma unroll
            for (int rr = 0; rr < 2; ++rr) {
                const int idx = rr * 1024 + tid * 4;          // 32x64, 2xfloat4
                const int row = idx >> 6, col = idx & 63;
                const int grow = rbase + row, gcol = bn + col;
                if (grow < M && gcol + 4 <= Ncap)
                    *(float4*)(C + (size_t)grow * ldc + gcol) =
                        *(const float4*)(lbuf + row * 68 + col);
            }
        }
    }
}

// Generic GEMM (128x64 tiles) with bijective XCD-chunk swizzle (nwg%8==0).
template <bool OUT_BF16>
__global__ __launch_bounds__(256, 4)
void hrr_gemm(const us16* __restrict__ A, const us16* __restrict__ B,
              void* __restrict__ C, int M, int N, int K,
              int lda, int ldb, int ldc, int Ncap, int swz) {
    __shared__ us16 smem[12288];        // 24 KB
    int bx = blockIdx.x, by = blockIdx.y;
    if (swz) {
        const int gx = gridDim.x;
        const int id = bx + gx * by;
        const int q = (gx * gridDim.y) >> 3;
        const int nid = (id & 7) * q + (id >> 3);
        bx = nid % gx; by = nid / gx;
    }
    gemm_core64<OUT_BF16>(A, B, C, M, N, K, lda, ldb, ldc, Ncap,
                          by * 128, bx * 64, smem);
}

// Fused builders (128x64 tiles): z<3 -> Mall_z = Tcs @ WT_z^T;
// z==3 -> MoutT = WoBf @ Sfb^T. Grid (17,9,4); out-of-range tiles exit.
__global__ __launch_bounds__(256, 4)
void hrr_gemm_builders(const us16* __restrict__ Tcs, const us16* __restrict__ WT,
                       us16* __restrict__ MallB, const us16* __restrict__ WoBf,
                       const us16* __restrict__ Sfb, us16* __restrict__ MoutB) {
    __shared__ us16 smem[12288];
    const int z = blockIdx.z;
    if (z < 3) {
        if (blockIdx.x >= 16) return;              // 16 n-tiles of 64 (N=1024)
        gemm_core64<true>(Tcs, WT + (size_t)z * D_ * D_,
                          MallB + (size_t)z * 1026 * 1024,
                          1026, 1024, 1024, 1024, 1024, 1024, 1024,
                          blockIdx.y * 128, blockIdx.x * 64, smem);
    } else {
        if (blockIdx.y >= 8) return;               // 8 m-tiles of 128 (M=1024)
        gemm_core64<true>(WoBf, Sfb, MoutB,
                          1024, KP2, 1024, 1024, 1024, KP2, KP2,
                          blockIdx.y * 128, blockIdx.x * 64, smem);
    }
}

// ---------------------------------------------------------------------------
// Main GEMM (R12b): Fall(4096 x 3078 used cols, bf16, ldc=LFP) = Xbf@MallB^T.
// 256x256 tile, BK=32, 512 threads = 8 waves (2M x 4N), per-wave 128x64 out.
// T4 COUNTED-vmcnt depth-3 pipeline: 4 LDS buffers (4 x 32 KB = 128 KB);
// per iter (32 iters):
//   s_waitcnt vmcnt(8)   // oldest stage done; 2 younger stages in flight
//   s_barrier            // all waves agree tile t staged (ONE barrier/iter)
//   STAGE(t+3)           // 4 global_load_lds into buffer freed at iter t-1
//   12 ds_read_b128 -> setprio(1) 32 MFMA setprio(0)
// Tail: vmcnt(4) at t=30, vmcnt(0) at t=31. Cover per stage ~3 iters >= HBM
// latency; loads never drain in steady state (m218 T4 mechanism).
// Race audit: buffers t..t+3 mod 4 distinct; STAGE(t+3) overwrites the
// buffer read at iter t-1, whose reads retired before barrier t.
// Granule XOR-swizzle both-sides ((row>>1)&3, 16-row-block invariant).
// ---------------------------------------------------------------------------
__global__ __launch_bounds__(512, 2)
void hrr_gemm_main(const us16* __restrict__ A, const us16* __restrict__ B,
                   us16* __restrict__ C) {
    __shared__ us16 smem[65536];          // 128 KB: A 4x8192 | B 4x8192
    us16* Asb = smem;
    us16* Bsb = smem + 32768;

    const int tid  = threadIdx.x;
    const int lane = tid & 63;
    const int wave = tid >> 6;

    // bijective XCD-chunk swizzle over 13x16 = 208 blocks (208 % 8 == 0)
    int id = blockIdx.x + 13 * blockIdx.y;
    id = (id & 7) * 26 + (id >> 3);
    const int bx = id % 13, by = id / 13;
    const int bm = by * 256, bn = bx * 256;

    // staging: 512 thr cover 128 rows x 32 cols per call (8 KB); 2 calls per
    // operand per tile. Source granule pre-swizzled g ^ ((row>>1)&3).
    const int srow = tid >> 2;                    // 0..127
    const int gsrc = (tid & 3) ^ ((srow >> 1) & 3);
    int ra0 = bm + srow;       if (ra0 > NTOK - 1) ra0 = NTOK - 1;
    int ra1 = bm + 128 + srow; if (ra1 > NTOK - 1) ra1 = NTOK - 1;
    int rb0 = bn + srow;       if (rb0 > LF - 1)   rb0 = LF - 1;
    int rb1 = bn + 128 + srow; if (rb1 > LF - 1)   rb1 = LF - 1;
    const us16* gA0 = A + (size_t)ra0 * 1024 + gsrc * 8;
    const us16* gA1 = A + (size_t)ra1 * 1024 + gsrc * 8;
    const us16* gB0 = B + (size_t)rb0 * 1024 + gsrc * 8;
    const us16* gB1 = B + (size_t)rb1 * 1024 + gsrc * 8;

    f32x4 acc[8][4];
#pragma unroll
    for (int i = 0; i < 8; i++)
#pragma unroll
        for (int j = 0; j < 4; j++) acc[i][j] = (f32x4){0.f, 0.f, 0.f, 0.f};

    const int wmw = (wave >> 2) * 128;    // wave M-offset (2 halves)
    const int wnw = (wave & 3) * 64;      // wave N-offset (4 quarters)
    const int fr  = lane & 15;
    const int gq8 = ((lane >> 4) ^ ((fr >> 1) & 3)) * 8;   // phys granule off

#define STAGE(buf, ko)                                             \
    do {                                                           \
        us16* a_ = Asb + (buf) * 8192 + wave * 512;                \
        us16* b_ = Bsb + (buf) * 8192 + wave * 512;                \
        gl_lds16(gA0 + (ko), a_);                                  \
        gl_lds16(gA1 + (ko), a_ + 4096);                           \
        gl_lds16(gB0 + (ko), b_);                                  \
        gl_lds16(gB1 + (ko), b_ + 4096);                           \
    } while (0)

    // prologue: 3 tiles in flight (12 outstanding vm ops per wave)
    STAGE(0, 0);
    STAGE(1, 32);
    STAGE(2, 64);

#pragma unroll 1
    for (int t = 0; t < 32; ++t) {
        if (t < 30)       asm volatile("s_waitcnt vmcnt(8)" ::: "memory");
        else if (t == 30) asm volatile("s_waitcnt vmcnt(4)" ::: "memory");
        else              asm volatile("s_waitcnt vmcnt(0)" ::: "memory");
        __builtin_amdgcn_s_barrier();
        asm volatile("" ::: "memory");

        if (t + 3 < 32) STAGE((t + 3) & 3, (t + 3) * 32);   // async refill

        const us16* Ac = Asb + (t & 3) * 8192;
        const us16* Bc = Bsb + (t & 3) * 8192;
        bf16x8 af[8], bfr[4];
#pragma unroll
        for (int i = 0; i < 8; ++i)
            af[i] = *(const bf16x8*)(Ac + (wmw + i * 16 + fr) * 32 + gq8);
#pragma unroll
        for (int j = 0; j < 4; ++j)
            bfr[j] = *(const bf16x8*)(Bc + (wnw + j * 16 + fr) * 32 + gq8);

        __builtin_amdgcn_s_setprio(1);
#pragma unroll
        for (int i = 0; i < 8; ++i)
#pragma unroll
            for (int j = 0; j < 4; ++j)
                acc[i][j] = __builtin_amdgcn_mfma_f32_16x16x32_bf16(
                    bfr[j], af[i], acc[i][j], 0, 0, 0);
        __builtin_amdgcn_s_setprio(0);
        asm volatile("" ::: "memory");
    }
#undef STAGE

    // ---- epilogue: per-wave LDS repack -> full-line bf16 row stores ----
    __syncthreads();
    float* lw = (float*)smem + wave * (32 * 68);     // 8.7 KB per wave
    const int cl = lane & 15;
    const int rq = (lane >> 4) * 4;
#pragma unroll
    for (int p = 0; p < 4; ++p) {
#pragma unroll
        for (int ii = 0; ii < 2; ++ii) {
            const int ifr = p * 2 + ii;
#pragma unroll
            for (int j = 0; j < 4; ++j)
                *(f32x4*)(lw + (ii * 16 + cl) * 68 + j * 16 + rq) = acc[ifr][j];
        }
        __syncthreads();
#pragma unroll
        for (int rr = 0; rr < 4; ++rr) {
            const int idx = rr * 512 + lane * 8;     // 32 rows x 64 cols
            const int row = idx >> 6, col = idx & 63;
            const int grow = bm + wmw + p * 32 + row;
            const int gcol = bn + wnw + col;
            if (gcol + 8 <= LFP) {
                const float* s = lw + row * 68 + col;
                uint4 o;
                o.x = (unsigned)f2b(s[0]) | ((unsigned)f2b(s[1]) << 16);
                o.y = (unsigned)f2b(s[2]) | ((unsigned)f2b(s[3]) << 16);
                o.z = (unsigned)f2b(s[4]) | ((unsigned)f2b(s[5]) << 16);
                o.w = (unsigned)f2b(s[6]) | ((unsigned)f2b(s[7]) << 16);
                *(uint4*)(C + (size_t)grow * LFP + gcol) = o;
            }
        }
        __syncthreads();
    }
}

// ---------------------------------------------------------------------------
// Scan phase 1: chunk sums. Grid (NCH, B_, 2) f-halves, 256 threads.
// T14 issue-early prefetch — next row's k/v loaded into regs right after the
// LDS-write barrier; compute phase + barrier hides the load latency.
// Fall u32 layout per row (R32=1568): q@0, k@513, v@1026.
// ---------------------------------------------------------------------------
__global__ __launch_bounds__(256, 4)
void hrr_scan_sums(const us16* __restrict__ Fall, const int* __restrict__ perms,
                   float* __restrict__ S) {
    const int n = blockIdx.x, b = blockIdx.y, half = blockIdx.z;
    const int tid = threadIdx.x;
    const int f0 = half * 256;
    __shared__ float2 kc[F_], vc[257];

    float aR[2][C_], aI[2][C_];
    int gg[2][C_];
#pragma unroll
    for (int i = 0; i < 2; i++) {
        const int f = (i == 0) ? (f0 + tid) : 512;
        const bool act = (i == 0) || (half == 1 && tid == 0);
#pragma unroll
        for (int c = 0; c < C_; c++) {
            gg[i][c] = act ? perms[c * F_ + f] : 0;
            aR[i][c] = aI[i][c] = 0.f;
        }
    }

    const unsigned* rowb =
        (const unsigned*)(Fall + (size_t)(b * T_ + n * TC) * LFP);
    const int R32 = LFP / 2;            // 1568 u32 per row

    unsigned rk0, rk1, rk2 = 0, rv0, rv1 = 0;
#define SFETCH(tl)                                                   \
    do {                                                             \
        const unsigned* r_ = rowb + (size_t)(tl) * R32;              \
        rk0 = r_[513 + tid];                                         \
        rk1 = r_[769 + tid];                                         \
        rv0 = r_[1026 + f0 + tid];                                   \
        if (tid == 0) { rk2 = r_[1025]; rv1 = r_[1538]; }            \
    } while (0)

    SFETCH(0);
    for (int tl = 0; tl < TC; tl++) {
        __syncthreads();                 // prev iter's LDS consumers done
        kc[tid]       = b2f2(rk0);
        kc[256 + tid] = b2f2(rk1);
        vc[tid]       = b2f2(rv0);
        if (tid == 0) { kc[512] = b2f2(rk2); if (half) vc[256] = b2f2(rv1); }
        __syncthreads();
        if (tl + 1 < TC) SFETCH(tl + 1); // issue next row early (async)
#pragma unroll
        for (int i = 0; i < 2; i++) {
            const int lv = (i == 0) ? tid : 256;
            if (i == 0 || (half == 1 && tid == 0)) {
                float2 v = vc[lv];
#pragma unroll
                for (int c = 0; c < C_; c++) {
                    float2 k = kc[gg[i][c]];
                    aR[i][c] += k.x * v.x - k.y * v.y;
                    aI[i][c] += k.x * v.y + k.y * v.x;
                }
            }
        }
    }
#undef SFETCH
#pragma unroll
    for (int i = 0; i < 2; i++) {
        const int f = (i == 0) ? (f0 + tid) : 512;
        if (i == 0 || (half == 1 && tid == 0)) {
#pragma unroll
            for (int c = 0; c < C_; c++) {
                size_t a = ((((size_t)c * B_ + b) * NCH + n) * F_ + f) * 2;
                S[a] = aR[i][c]; S[a + 1] = aI[i][c];
            }
        }
    }
}

// ---------------------------------------------------------------------------
// Scan phase 2: exclusive prefix over chunks, per (c,b,f). 8-way unrolled.
// ---------------------------------------------------------------------------
__global__ void hrr_scan_prefix(float* __restrict__ S) {
    int tid = blockIdx.x * 256 + threadIdx.x;
    if (tid >= C_ * B_ * F_) return;
    int c = tid / (B_ * F_);
    int r = tid % (B_ * F_);
    int b = r / F_, f = r % F_;
    size_t base = (((size_t)c * B_ + b) * NCH) * F_ + f;
    float runR = 0.f, runI = 0.f;
    for (int n0 = 0; n0 < NCH; n0 += 8) {
        float tR[8], tI[8];
#pragma unroll
        for (int u = 0; u < 8; u++) {
            size_t a = (base + (size_t)(n0 + u) * F_) * 2;
            tR[u] = S[a]; tI[u] = S[a + 1];
        }
#pragma unroll
        for (int u = 0; u < 8; u++) {
            size_t a = (base + (size_t)(n0 + u) * F_) * 2;
            S[a] = runR; S[a + 1] = runI;
            runR += tR[u]; runI += tI[u];
        }
    }
}

// ---------------------------------------------------------------------------
// Scan phase 3: running kv in regs, r = mean_c kv*conj(fqp) -> Rcat.
// T14 issue-early prefetch of next row's q/k/v (same pattern as sums).
// ---------------------------------------------------------------------------
__global__ __launch_bounds__(256, 4)
void hrr_scan_apply(const us16* __restrict__ Fall, const int* __restrict__ perms,
                    const float* __restrict__ S, us16* __restrict__ Rcat) {
    const int n = blockIdx.x, b = blockIdx.y, half = blockIdx.z;
    const int tid = threadIdx.x;
    const int f0 = half * 256;
    __shared__ float2 qc[F_], kc[F_], vc[257];

    float kvR[2][C_], kvI[2][C_];
    int gg[2][C_];
#pragma unroll
    for (int i = 0; i < 2; i++) {
        const int f = (i == 0) ? (f0 + tid) : 512;
        const bool act = (i == 0) || (half == 1 && tid == 0);
#pragma unroll
        for (int c = 0; c < C_; c++) {
            gg[i][c] = act ? perms[c * F_ + f] : 0;
            if (act) {
                size_t a = ((((size_t)c * B_ + b) * NCH + n) * F_ + f) * 2;
                kvR[i][c] = S[a]; kvI[i][c] = S[a + 1];
            } else { kvR[i][c] = 0.f; kvI[i][c] = 0.f; }
        }
    }

    const unsigned* rowb =
        (const unsigned*)(Fall + (size_t)(b * T_ + n * TC) * LFP);
    const int R32 = LFP / 2;            // 1568 u32 per row

    unsigned rq0, rq1, rq2 = 0, rk0, rk1, rk2 = 0, rv0, rv1 = 0;
#define AFETCH(tl)                                                   \
    do {                                                             \
        const unsigned* r_ = rowb + (size_t)(tl) * R32;              \
        rq0 = r_[tid];       rq1 = r_[256 + tid];                    \
        rk0 = r_[513 + tid]; rk1 = r_[769 + tid];                    \
        rv0 = r_[1026 + f0 + tid];                                   \
        if (tid == 0) { rq2 = r_[512]; rk2 = r_[1025]; rv1 = r_[1538]; } \
    } while (0)

    AFETCH(0);
    for (int tl = 0; tl < TC; tl++) {
        const int tt = b * T_ + n * TC + tl;
        __syncthreads();                 // prev iter's LDS consumers done
        qc[tid]       = b2f2(rq0);
        qc[256 + tid] = b2f2(rq1);
        kc[tid]       = b2f2(rk0);
        kc[256 + tid] = b2f2(rk1);
        vc[tid]       = b2f2(rv0);
        if (tid == 0) {
            qc[512] = b2f2(rq2); kc[512] = b2f2(rk2);
            if (half) vc[256] = b2f2(rv1);
        }
        __syncthreads();
        if (tl + 1 < TC) AFETCH(tl + 1); // issue next row early (async)
        unsigned* out32 = (unsigned*)(Rcat + (size_t)tt * KP2);
#pragma unroll
        for (int i = 0; i < 2; i++) {
            const int f = (i == 0) ? (f0 + tid) : 512;
            const int lv = (i == 0) ? tid : 256;
            if (i == 0 || (half == 1 && tid == 0)) {
                float2 v = vc[lv];
                float accR = 0.f, accI = 0.f;
#pragma unroll
                for (int c = 0; c < C_; c++) {
                    int g = gg[i][c];
                    float2 k = kc[g];
                    float nR = kvR[i][c] + k.x * v.x - k.y * v.y;
                    float nI = kvI[i][c] + k.x * v.y + k.y * v.x;
                    kvR[i][c] = nR; kvI[i][c] = nI;
                    float2 q = qc[g];
                    accR += nR * q.x + nI * q.y;
                    accI += nI * q.x - nR * q.y;
                }
                out32[f] = (unsigned)f2b(accR * 0.1f)
                         | ((unsigned)f2b(accI * 0.1f) << 16);
            }
        }
        if (half == 0 && tid < 15)                  // zero pad cols 1026..1055
            out32[513 + tid] = 0;
    }
#undef AFETCH
}

// ---------------------------------------------------------------------------
extern "C" void kernel_launch(void* const* d_in, const int* in_sizes, int n_in,
                              void* d_out, int out_size, void* d_ws, size_t ws_size,
                              hipStream_t stream) {
    const float* x  = (const float*)d_in[0];
    const float* Wq = (const float*)d_in[1];
    const float* Wk = (const float*)d_in[2];
    const float* Wv = (const float*)d_in[3];
    const float* Wo = (const float*)d_in[4];
    const int* perms = (const int*)d_in[5];
    float* out = (float*)d_out;

    char* ws = (char*)d_ws;
    us16* Xbf   = (us16*)(ws + O_XBF);
    us16* WT    = (us16*)(ws + O_WT);
    us16* WoBf  = (us16*)(ws + O_WOBF);
    us16* Tcs   = (us16*)(ws + O_TCS);
    us16* Sfb   = (us16*)(ws + O_SFB);
    us16* MallB = (us16*)(ws + O_MALLB);
    us16* MoutB = (us16*)(ws + O_MOUTB);
    us16* Rcat  = (us16*)(ws + O_RCAT);
    us16* Fall  = (us16*)(ws + O_FALL);
    float* Ssc  = (float*)(ws + O_SSCAN);

    // fused prep: cvt x / cvt Wo / transpose x3 / Tcs+Sfb fused / Sfb pad
    hrr_prep<<<12416, 256, 0, stream>>>(x, Wq, Wk, Wv, Wo, Xbf, WT, WoBf, Tcs, Sfb);

    // fused builders: Mall x3 + MoutT, one dispatch, 128x64 tiles
    hrr_gemm_builders<<<dim3(17, 9, 4), 256, 0, stream>>>(Tcs, WT, MallB, WoBf, Sfb, MoutB);

    // main GEMM: 256x256 counted-vmcnt pipelined kernel, grid 13x16 = 208
    hrr_gemm_main<<<dim3(13, 16), 512, 0, stream>>>(Xbf, MallB, Fall);

    // chunked causal scan (NCH=128, TC=16; scan kernels T14-prefetched)
    hrr_scan_sums<<<dim3(NCH, B_, 2), 256, 0, stream>>>(Fall, perms, Ssc);
    hrr_scan_prefix<<<(C_ * B_ * F_ + 255) / 256, 256, 0, stream>>>(Ssc);
    hrr_scan_apply<<<dim3(NCH, B_, 2), 256, 0, stream>>>(Fall, perms, Ssc, Rcat);

    // output GEMM: out(4096x1024 fp32) = Rcat(4096x1056) @ MoutB^T
    // 128x64 tiles -> 16x32 = 512 blocks (2/CU), XCD swizzle
    hrr_gemm<false><<<dim3(16, 32), 256, 0, stream>>>(
        Rcat, MoutB, out, NTOK, D_, KP2, KP2, KP2, D_, D_, 1);
}